// Round 1
// baseline (1175.182 us; speedup 1.0000x reference)
//
#include <hip/hip_runtime.h>
#include <hip/hip_bf16.h>
#include <math.h>

#define N_NODES 50000
#define N_EDGES 400000
#define E_TOT   (N_EDGES + N_NODES)   // self loops appended
#define HEADS   8
#define HID     64
#define HC      (HEADS * HID)         // 512

__device__ __forceinline__ float elu1(float x) { return x > 0.f ? x : __expf(x) - 1.f; }

// ---------------- CSR build (by dst) ----------------
__global__ void hist_kernel(const int* __restrict__ dst, int* __restrict__ deg) {
    int e = blockIdx.x * blockDim.x + threadIdx.x;
    if (e >= E_TOT) return;
    int d = (e < N_EDGES) ? dst[e] : (e - N_EDGES);
    atomicAdd(&deg[d], 1);
}

__global__ __launch_bounds__(1024) void scan_kernel(const int* __restrict__ deg,
                                                    int* __restrict__ rowptr,
                                                    int* __restrict__ cursor) {
    __shared__ int part[1024];
    const int CH = (N_NODES + 1023) / 1024;  // 49
    int t = threadIdx.x;
    int base = t * CH;
    int sum = 0;
    for (int i = 0; i < CH; ++i) {
        int idx = base + i;
        if (idx < N_NODES) sum += deg[idx];
    }
    part[t] = sum;
    __syncthreads();
    for (int off = 1; off < 1024; off <<= 1) {
        int v = part[t];
        int add = (t >= off) ? part[t - off] : 0;
        __syncthreads();
        part[t] = v + add;
        __syncthreads();
    }
    int run = part[t] - sum;  // exclusive prefix of this chunk
    for (int i = 0; i < CH; ++i) {
        int idx = base + i;
        if (idx < N_NODES) {
            rowptr[idx] = run;
            cursor[idx] = run;
            run += deg[idx];
        }
    }
    if (t == 1023) rowptr[N_NODES] = part[1023];
}

__global__ void scatter_kernel(const int* __restrict__ srcrow, const int* __restrict__ dstrow,
                               int* __restrict__ cursor, int* __restrict__ src_sorted) {
    int e = blockIdx.x * blockDim.x + threadIdx.x;
    if (e >= E_TOT) return;
    int s, d;
    if (e < N_EDGES) { s = srcrow[e]; d = dstrow[e]; }
    else             { s = d = e - N_EDGES; }
    int pos = atomicAdd(&cursor[d], 1);
    src_sorted[pos] = s;
}

// ---------------- Layer 1 GEMM: [N,5] @ [5,512] ----------------
__global__ void gemm5_kernel(const float* __restrict__ x, const float* __restrict__ W,
                             float* __restrict__ h) {
    int gid = blockIdx.x * blockDim.x + threadIdx.x;
    if (gid >= N_NODES * HC) return;
    int n = gid >> 9, c = gid & 511;
    const float* xr = x + n * 5;
    float acc = xr[0] * W[c] + xr[1] * W[512 + c] + xr[2] * W[1024 + c] +
                xr[3] * W[1536 + c] + xr[4] * W[2048 + c];
    h[gid] = acc;
}

// ---------------- fp32 tiled GEMM: [M,K] @ [K,N], K%16==0, N%64==0 ----------------
__global__ __launch_bounds__(256) void gemm_f32(const float* __restrict__ A,
                                                const float* __restrict__ B,
                                                float* __restrict__ C,
                                                int M, int N, int K) {
    constexpr int BM = 64, BN = 64, BK = 16;
    __shared__ float As[BK][BM + 4];  // As[k][m]
    __shared__ float Bs[BK][BN + 4];  // Bs[k][n]
    int t = threadIdx.x;
    int tx = t & 15, ty = t >> 4;
    int m0 = blockIdx.y * BM, n0 = blockIdx.x * BN;
    float acc[4][4] = {};
    for (int k0 = 0; k0 < K; k0 += BK) {
        {   // A tile: 64 m-rows x 16 k-cols
            int k = t & 15, mrow = t >> 4;
            #pragma unroll
            for (int pass = 0; pass < 4; ++pass) {
                int m = mrow + pass * 16;
                int gm = m0 + m;
                As[k][m] = (gm < M) ? A[(size_t)gm * K + k0 + k] : 0.f;
            }
        }
        {   // B tile: 16 k-rows x 64 n-cols
            int n = t & 63, krow = t >> 6;
            #pragma unroll
            for (int pass = 0; pass < 4; ++pass) {
                int k = krow + pass * 4;
                Bs[k][n] = B[(size_t)(k0 + k) * N + n0 + n];
            }
        }
        __syncthreads();
        #pragma unroll
        for (int kk = 0; kk < BK; ++kk) {
            const float4 a4 = *(const float4*)&As[kk][ty * 4];
            const float4 b4 = *(const float4*)&Bs[kk][tx * 4];
            const float ar[4] = {a4.x, a4.y, a4.z, a4.w};
            const float br[4] = {b4.x, b4.y, b4.z, b4.w};
            #pragma unroll
            for (int i = 0; i < 4; ++i)
                #pragma unroll
                for (int j = 0; j < 4; ++j)
                    acc[i][j] = fmaf(ar[i], br[j], acc[i][j]);
        }
        __syncthreads();
    }
    #pragma unroll
    for (int i = 0; i < 4; ++i) {
        int gm = m0 + ty * 4 + i;
        if (gm < M) {
            float4 v = make_float4(acc[i][0], acc[i][1], acc[i][2], acc[i][3]);
            *(float4*)&C[(size_t)gm * N + n0 + tx * 4] = v;
        }
    }
}

// ---------------- attention scores: s_src/s_dst [N,H] ----------------
template <int H, int C>
__global__ void score_kernel(const float* __restrict__ h, const float* __restrict__ a_src,
                             const float* __restrict__ a_dst,
                             float* __restrict__ ssrc, float* __restrict__ sdst) {
    int gid = blockIdx.x * blockDim.x + threadIdx.x;
    if (gid >= N_NODES * H) return;
    int n = gid / H, hh = gid % H;
    const float* hp  = h + (size_t)n * (H * C) + hh * C;
    const float* asp = a_src + hh * C;
    const float* adp = a_dst + hh * C;
    float s1 = 0.f, s2 = 0.f;
    #pragma unroll
    for (int k = 0; k < C; k += 4) {
        float4 hv = *(const float4*)(hp + k);
        float4 av = *(const float4*)(asp + k);
        float4 dv = *(const float4*)(adp + k);
        s1 += hv.x * av.x + hv.y * av.y + hv.z * av.z + hv.w * av.w;
        s2 += hv.x * dv.x + hv.y * dv.y + hv.z * dv.z + hv.w * dv.w;
    }
    ssrc[gid] = s1;
    sdst[gid] = s2;
}

// ---------------- per-(dst,head) softmax: writes unnormalized p and 1/denom ----------------
template <int H>
__global__ void softmax_kernel(const int* __restrict__ rowptr, const int* __restrict__ srcs,
                               const float* __restrict__ ssrc, const float* __restrict__ sdst,
                               float* __restrict__ p, float* __restrict__ rden) {
    int gid = blockIdx.x * blockDim.x + threadIdx.x;
    if (gid >= N_NODES * H) return;
    int n = gid / H, hh = gid % H;
    int lo = rowptr[n], hi = rowptr[n + 1];
    float sd = sdst[gid];
    float mx = -3.4e38f;
    for (int j = lo; j < hi; ++j) {
        float v = ssrc[srcs[j] * H + hh] + sd;
        v = v > 0.f ? v : 0.2f * v;
        mx = fmaxf(mx, v);
    }
    float sum = 0.f;
    for (int j = lo; j < hi; ++j) {
        float v = ssrc[srcs[j] * H + hh] + sd;
        v = v > 0.f ? v : 0.2f * v;
        float pe = __expf(v - mx);
        p[(size_t)j * H + hh] = pe;
        sum += pe;
    }
    rden[gid] = 1.f / (sum + 1e-16f);
}

// ---------------- gather-aggregate + bias + ELU ----------------
template <int H, int C, int TPB>
__global__ __launch_bounds__(TPB) void agg_kernel(const float* __restrict__ h,
                                                  const float* __restrict__ p,
                                                  const int* __restrict__ rowptr,
                                                  const int* __restrict__ srcs,
                                                  const float* __restrict__ rden,
                                                  const float* __restrict__ bias,
                                                  float* __restrict__ out) {
    constexpr int HCt = H * C;
    constexpr int CPT = HCt / TPB;
    int n = blockIdx.x;
    int lo = rowptr[n], hi = rowptr[n + 1];
    float acc[CPT] = {};
    int cc[CPT], hh[CPT];
    float rd[CPT];
    #pragma unroll
    for (int i = 0; i < CPT; ++i) {
        cc[i] = threadIdx.x + i * TPB;
        hh[i] = cc[i] / C;
        rd[i] = rden[n * H + hh[i]];
    }
    for (int j = lo; j < hi; ++j) {
        int s = srcs[j];
        const float* hr = h + (size_t)s * HCt;
        #pragma unroll
        for (int i = 0; i < CPT; ++i) {
            float pj = p[(size_t)j * H + hh[i]];
            acc[i] = fmaf(pj, hr[cc[i]], acc[i]);
        }
    }
    #pragma unroll
    for (int i = 0; i < CPT; ++i) {
        float v = acc[i] * rd[i] + bias[cc[i]];
        out[(size_t)n * HCt + cc[i]] = elu1(v);
    }
}

// ---------------- classifier: sigmoid(h3 @ Wc + bc) ----------------
__global__ void cls_kernel(const float* __restrict__ h, const float* __restrict__ Wc,
                           const float* __restrict__ bc, float* __restrict__ out) {
    int n = blockIdx.x * blockDim.x + threadIdx.x;
    if (n >= N_NODES) return;
    const float* hp = h + (size_t)n * 64;
    float s = bc[0];
    #pragma unroll
    for (int k = 0; k < 64; k += 4) {
        float4 hv = *(const float4*)(hp + k);
        float4 wv = *(const float4*)(Wc + k);
        s += hv.x * wv.x + hv.y * wv.y + hv.z * wv.z + hv.w * wv.w;
    }
    out[n] = 1.f / (1.f + __expf(-s));
}

extern "C" void kernel_launch(void* const* d_in, const int* in_sizes, int n_in,
                              void* d_out, int out_size, void* d_ws, size_t ws_size,
                              hipStream_t stream) {
    const float* x   = (const float*)d_in[0];
    const int*   ei  = (const int*)d_in[1];
    const int* src_row = ei;
    const int* dst_row = ei + N_EDGES;
    const float* W1  = (const float*)d_in[2];
    const float* as1 = (const float*)d_in[3];
    const float* ad1 = (const float*)d_in[4];
    const float* b1  = (const float*)d_in[5];
    const float* W2  = (const float*)d_in[6];
    const float* as2 = (const float*)d_in[7];
    const float* ad2 = (const float*)d_in[8];
    const float* b2  = (const float*)d_in[9];
    const float* W3  = (const float*)d_in[10];
    const float* as3 = (const float*)d_in[11];
    const float* ad3 = (const float*)d_in[12];
    const float* b3  = (const float*)d_in[13];
    const float* Wc  = (const float*)d_in[14];
    const float* bc  = (const float*)d_in[15];

    char* w = (char*)d_ws;
    auto alloc = [&](size_t bytes) -> void* {
        void* ptr = (void*)w;
        w += (bytes + 255) & ~(size_t)255;
        return ptr;
    };
    int*   deg    = (int*)alloc((size_t)N_NODES * 4);
    int*   rowptr = (int*)alloc((size_t)(N_NODES + 1) * 4);
    int*   cursor = (int*)alloc((size_t)N_NODES * 4);
    int*   srcs   = (int*)alloc((size_t)E_TOT * 4);
    float* pbuf   = (float*)alloc((size_t)E_TOT * HEADS * 4);
    float* ssrc   = (float*)alloc((size_t)N_NODES * HEADS * 4);
    float* sdst   = (float*)alloc((size_t)N_NODES * HEADS * 4);
    float* rden   = (float*)alloc((size_t)N_NODES * HEADS * 4);
    float* hA     = (float*)alloc((size_t)N_NODES * HC * 4);
    float* hB     = (float*)alloc((size_t)N_NODES * HC * 4);

    hipMemsetAsync(deg, 0, (size_t)N_NODES * 4, stream);

    const int EB = (E_TOT + 255) / 256;
    hist_kernel<<<EB, 256, 0, stream>>>(dst_row, deg);
    scan_kernel<<<1, 1024, 0, stream>>>(deg, rowptr, cursor);
    scatter_kernel<<<EB, 256, 0, stream>>>(src_row, dst_row, cursor, srcs);

    const int NHB = (N_NODES * HEADS + 255) / 256;
    const int NB  = (N_NODES + 255) / 256;

    // ---- layer 1: x[N,5] -> hA[N,512] -> attn -> hB[N,512] ----
    gemm5_kernel<<<(N_NODES * HC + 255) / 256, 256, 0, stream>>>(x, W1, hA);
    score_kernel<8, 64><<<NHB, 256, 0, stream>>>(hA, as1, ad1, ssrc, sdst);
    softmax_kernel<8><<<NHB, 256, 0, stream>>>(rowptr, srcs, ssrc, sdst, pbuf, rden);
    agg_kernel<8, 64, 256><<<N_NODES, 256, 0, stream>>>(hA, pbuf, rowptr, srcs, rden, b1, hB);

    // ---- layer 2: hB[N,512] @ W2 -> hA -> attn -> hB ----
    gemm_f32<<<dim3(512 / 64, (N_NODES + 63) / 64), 256, 0, stream>>>(hB, W2, hA, N_NODES, 512, 512);
    score_kernel<8, 64><<<NHB, 256, 0, stream>>>(hA, as2, ad2, ssrc, sdst);
    softmax_kernel<8><<<NHB, 256, 0, stream>>>(rowptr, srcs, ssrc, sdst, pbuf, rden);
    agg_kernel<8, 64, 256><<<N_NODES, 256, 0, stream>>>(hA, pbuf, rowptr, srcs, rden, b2, hB);

    // ---- layer 3: hB[N,512] @ W3[512,64] -> hA[N,64] -> attn (1 head) -> hB[N,64] ----
    gemm_f32<<<dim3(64 / 64, (N_NODES + 63) / 64), 256, 0, stream>>>(hB, W3, hA, N_NODES, 64, 512);
    score_kernel<1, 64><<<NB, 256, 0, stream>>>(hA, as3, ad3, ssrc, sdst);
    softmax_kernel<1><<<NB, 256, 0, stream>>>(rowptr, srcs, ssrc, sdst, pbuf, rden);
    agg_kernel<1, 64, 64><<<N_NODES, 64, 0, stream>>>(hA, pbuf, rowptr, srcs, rden, b3, hB);

    // ---- classifier ----
    cls_kernel<<<NB, 256, 0, stream>>>(hB, Wc, bc, (float*)d_out);
}

// Round 2
// 879.740 us; speedup vs baseline: 1.3358x; 1.3358x over previous
//
#include <hip/hip_runtime.h>
#include <hip/hip_bf16.h>
#include <math.h>

#define N_NODES 50000
#define N_EDGES 400000
#define E_TOT   (N_EDGES + N_NODES)   // self loops appended
#define HEADS   8
#define HID     64
#define HC      (HEADS * HID)         // 512

typedef __attribute__((ext_vector_type(8))) short bf16x8;  // 8 bf16 (4 VGPRs)
typedef __attribute__((ext_vector_type(4))) float f32x4;

__device__ __forceinline__ float elu1(float x) { return x > 0.f ? x : __expf(x) - 1.f; }

// round-to-nearest-even fp32 -> bf16 (raw ushort)
__device__ __forceinline__ unsigned short f2bf(float x) {
    unsigned u = __float_as_uint(x);
    unsigned r = (u + 0x7FFFu + ((u >> 16) & 1u)) >> 16;
    return (unsigned short)r;
}
__device__ __forceinline__ float bf2f(unsigned short h) {
    return __uint_as_float(((unsigned)h) << 16);
}

// ---------------- CSR build (by dst) ----------------
__global__ void hist_kernel(const int* __restrict__ dst, int* __restrict__ deg) {
    int e = blockIdx.x * blockDim.x + threadIdx.x;
    if (e >= E_TOT) return;
    int d = (e < N_EDGES) ? dst[e] : (e - N_EDGES);
    atomicAdd(&deg[d], 1);
}

__global__ __launch_bounds__(1024) void scan_kernel(const int* __restrict__ deg,
                                                    int* __restrict__ rowptr,
                                                    int* __restrict__ cursor) {
    __shared__ int part[1024];
    const int CH = (N_NODES + 1023) / 1024;  // 49
    int t = threadIdx.x;
    int base = t * CH;
    int sum = 0;
    for (int i = 0; i < CH; ++i) {
        int idx = base + i;
        if (idx < N_NODES) sum += deg[idx];
    }
    part[t] = sum;
    __syncthreads();
    for (int off = 1; off < 1024; off <<= 1) {
        int v = part[t];
        int add = (t >= off) ? part[t - off] : 0;
        __syncthreads();
        part[t] = v + add;
        __syncthreads();
    }
    int run = part[t] - sum;  // exclusive prefix of this chunk
    for (int i = 0; i < CH; ++i) {
        int idx = base + i;
        if (idx < N_NODES) {
            rowptr[idx] = run;
            cursor[idx] = run;
            run += deg[idx];
        }
    }
    if (t == 1023) rowptr[N_NODES] = part[1023];
}

__global__ void scatter_kernel(const int* __restrict__ srcrow, const int* __restrict__ dstrow,
                               int* __restrict__ cursor, int* __restrict__ src_sorted) {
    int e = blockIdx.x * blockDim.x + threadIdx.x;
    if (e >= E_TOT) return;
    int s, d;
    if (e < N_EDGES) { s = srcrow[e]; d = dstrow[e]; }
    else             { s = d = e - N_EDGES; }
    int pos = atomicAdd(&cursor[d], 1);
    src_sorted[pos] = s;
}

// ---------------- Layer 1 GEMM: [N,5] @ [5,512] (K too small for MFMA) ----------------
__global__ void gemm5_kernel(const float* __restrict__ x, const float* __restrict__ W,
                             float* __restrict__ h) {
    int gid = blockIdx.x * blockDim.x + threadIdx.x;
    if (gid >= N_NODES * HC) return;
    int n = gid >> 9, c = gid & 511;
    const float* xr = x + n * 5;
    float acc = xr[0] * W[c] + xr[1] * W[512 + c] + xr[2] * W[1024 + c] +
                xr[3] * W[1536 + c] + xr[4] * W[2048 + c];
    h[gid] = acc;
}

// ---------------- W -> W^T split (hi/lo bf16): W[512][NCOL] -> Wt[NCOL][512] ----------------
template <int NCOL>
__global__ void wsplit_kernel(const float* __restrict__ W, unsigned short* __restrict__ hi,
                              unsigned short* __restrict__ lo) {
    int idx = blockIdx.x * 256 + threadIdx.x;
    if (idx >= 512 * NCOL) return;
    int k = idx / NCOL, n = idx % NCOL;
    float v = W[idx];
    unsigned short h = f2bf(v);
    unsigned short l = f2bf(v - bf2f(h));
    hi[(size_t)n * 512 + k] = h;
    lo[(size_t)n * 512 + k] = l;
}

// ---------------- split-bf16 MFMA GEMM ----------------
// A (hi/lo): [M][512] bf16 row-major. B (hi/lo): [Ncols][512] bf16 (i.e. W^T). C: [M][Nout] fp32.
// LDS tile layout: per row, 64B (32 bf16 of the K-window); 16B-slot p holds logical
// k-chunk g = p ^ ((row>>1)&3)  (XOR swizzle: staged via pre-swizzled global source,
// read back with the same XOR -> frag ds_read_b128 is ~2-way conflict = free).
template <int ROWS, int NW>
__device__ __forceinline__ void stage_tile(const unsigned short* __restrict__ src, int row0,
                                           int maxRow, int k0, char* lds, int wave, int lane) {
    constexpr int CHUNKS = ROWS / 16;  // 1KB chunks (16 rows x 64B)
    for (int c = wave; c < CHUNKS; c += NW) {
        int r = c * 16 + (lane >> 2);
        int p = lane & 3;
        int g = p ^ ((r >> 1) & 3);
        int gr = row0 + r;
        if (gr > maxRow) gr = maxRow;  // tail clamp; result write-guarded
        const unsigned short* gp = src + (size_t)gr * 512 + k0 + g * 8;
        __builtin_amdgcn_global_load_lds((const __attribute__((address_space(1))) void*)gp,
                                         (__attribute__((address_space(3))) void*)(lds + c * 1024),
                                         16, 0, 0);
    }
}

template <int BN, int WM, int WN>
__global__ __launch_bounds__(WM * WN * 64) void gemm_mfma(
    const unsigned short* __restrict__ Ahi, const unsigned short* __restrict__ Alo,
    const unsigned short* __restrict__ Bhi, const unsigned short* __restrict__ Blo,
    float* __restrict__ C, int M, int Nout, int maxRowB) {
    constexpr int BM = 128;
    constexpr int NW = WM * WN;
    __shared__ __attribute__((aligned(16))) char ldsAhi[BM * 64];
    __shared__ __attribute__((aligned(16))) char ldsAlo[BM * 64];
    __shared__ __attribute__((aligned(16))) char ldsBhi[BN * 64];
    __shared__ __attribute__((aligned(16))) char ldsBlo[BN * 64];
    const int t = threadIdx.x, lane = t & 63, wave = t >> 6;
    const int wr = wave / WN, wc = wave % WN;
    const int m0 = blockIdx.y * BM, n0 = blockIdx.x * BN;

    // per-thread frag LDS byte offsets (constant across K-steps)
    int offA[4], offB[4];
#pragma unroll
    for (int s = 0; s < 4; ++s) {
        int rA = wr * 64 + s * 16 + (lane & 15);
        offA[s] = rA * 64 + ((((lane >> 4) ^ ((rA >> 1) & 3))) << 4);
        int rB = wc * 64 + s * 16 + (lane & 15);
        offB[s] = rB * 64 + ((((lane >> 4) ^ ((rB >> 1) & 3))) << 4);
    }

    f32x4 acc[4][4] = {};

    for (int k0 = 0; k0 < 512; k0 += 32) {
        stage_tile<BM, NW>(Ahi, m0, M - 1, k0, ldsAhi, wave, lane);
        stage_tile<BM, NW>(Alo, m0, M - 1, k0, ldsAlo, wave, lane);
        stage_tile<BN, NW>(Bhi, n0, maxRowB, k0, ldsBhi, wave, lane);
        stage_tile<BN, NW>(Blo, n0, maxRowB, k0, ldsBlo, wave, lane);
        __syncthreads();  // compiler drains vmcnt before barrier -> LDS valid

        bf16x8 ah[4], al[4], bh[4], bl[4];
#pragma unroll
        for (int s = 0; s < 4; ++s) {
            ah[s] = *(const bf16x8*)(ldsAhi + offA[s]);
            al[s] = *(const bf16x8*)(ldsAlo + offA[s]);
            bh[s] = *(const bf16x8*)(ldsBhi + offB[s]);
            bl[s] = *(const bf16x8*)(ldsBlo + offB[s]);
        }
#pragma unroll
        for (int i = 0; i < 4; ++i)
#pragma unroll
            for (int j = 0; j < 4; ++j) {
                acc[i][j] = __builtin_amdgcn_mfma_f32_16x16x32_bf16(ah[i], bh[j], acc[i][j], 0, 0, 0);
                acc[i][j] = __builtin_amdgcn_mfma_f32_16x16x32_bf16(ah[i], bl[j], acc[i][j], 0, 0, 0);
                acc[i][j] = __builtin_amdgcn_mfma_f32_16x16x32_bf16(al[i], bh[j], acc[i][j], 0, 0, 0);
            }
        __syncthreads();
    }

    // C/D layout (m89-verified): col = lane&15, row = (lane>>4)*4 + reg
#pragma unroll
    for (int i = 0; i < 4; ++i) {
        int row = m0 + wr * 64 + i * 16 + ((lane >> 4) << 2);
#pragma unroll
        for (int j = 0; j < 4; ++j) {
            int col = n0 + wc * 64 + j * 16 + (lane & 15);
            f32x4 v = acc[i][j];
#pragma unroll
            for (int r = 0; r < 4; ++r) {
                if (row + r < M) C[(size_t)(row + r) * Nout + col] = v[r];
            }
        }
    }
}

// ---------------- attention scores: s_src/s_dst [N,H] ----------------
template <int H, int C>
__global__ void score_kernel(const float* __restrict__ h, const float* __restrict__ a_src,
                             const float* __restrict__ a_dst,
                             float* __restrict__ ssrc, float* __restrict__ sdst) {
    int gid = blockIdx.x * blockDim.x + threadIdx.x;
    if (gid >= N_NODES * H) return;
    int n = gid / H, hh = gid % H;
    const float* hp  = h + (size_t)n * (H * C) + hh * C;
    const float* asp = a_src + hh * C;
    const float* adp = a_dst + hh * C;
    float s1 = 0.f, s2 = 0.f;
#pragma unroll
    for (int k = 0; k < C; k += 4) {
        float4 hv = *(const float4*)(hp + k);
        float4 av = *(const float4*)(asp + k);
        float4 dv = *(const float4*)(adp + k);
        s1 += hv.x * av.x + hv.y * av.y + hv.z * av.z + hv.w * av.w;
        s2 += hv.x * dv.x + hv.y * dv.y + hv.z * dv.z + hv.w * dv.w;
    }
    ssrc[gid] = s1;
    sdst[gid] = s2;
}

// ---------------- per-(dst,head) softmax: unnormalized p and 1/denom ----------------
template <int H>
__global__ void softmax_kernel(const int* __restrict__ rowptr, const int* __restrict__ srcs,
                               const float* __restrict__ ssrc, const float* __restrict__ sdst,
                               float* __restrict__ p, float* __restrict__ rden) {
    int gid = blockIdx.x * blockDim.x + threadIdx.x;
    if (gid >= N_NODES * H) return;
    int n = gid / H, hh = gid % H;
    int lo = rowptr[n], hi = rowptr[n + 1];
    float sd = sdst[gid];
    float mx = -3.4e38f;
    for (int j = lo; j < hi; ++j) {
        float v = ssrc[srcs[j] * H + hh] + sd;
        v = v > 0.f ? v : 0.2f * v;
        mx = fmaxf(mx, v);
    }
    float sum = 0.f;
    for (int j = lo; j < hi; ++j) {
        float v = ssrc[srcs[j] * H + hh] + sd;
        v = v > 0.f ? v : 0.2f * v;
        float pe = __expf(v - mx);
        p[(size_t)j * H + hh] = pe;
        sum += pe;
    }
    rden[gid] = 1.f / (sum + 1e-16f);
}

// ---------------- gather-aggregate + bias + ELU (+ optional bf16 hi/lo split out) ----------------
template <int H, int C, int TPB, bool SPLIT>
__global__ __launch_bounds__(TPB) void agg_kernel(const float* __restrict__ h,
                                                  const float* __restrict__ p,
                                                  const int* __restrict__ rowptr,
                                                  const int* __restrict__ srcs,
                                                  const float* __restrict__ rden,
                                                  const float* __restrict__ bias,
                                                  float* __restrict__ outF,
                                                  unsigned short* __restrict__ outHi,
                                                  unsigned short* __restrict__ outLo) {
    constexpr int HCt = H * C;
    constexpr int CPT = HCt / TPB;
    int n = blockIdx.x;
    int lo = rowptr[n], hi = rowptr[n + 1];
    float acc[CPT] = {};
    int cc[CPT], hh[CPT];
    float rd[CPT];
#pragma unroll
    for (int i = 0; i < CPT; ++i) {
        cc[i] = threadIdx.x + i * TPB;
        hh[i] = cc[i] / C;
        rd[i] = rden[n * H + hh[i]];
    }
    for (int j = lo; j < hi; ++j) {
        int s = srcs[j];
        const float* hr = h + (size_t)s * HCt;
#pragma unroll
        for (int i = 0; i < CPT; ++i) {
            float pj = p[(size_t)j * H + hh[i]];
            acc[i] = fmaf(pj, hr[cc[i]], acc[i]);
        }
    }
#pragma unroll
    for (int i = 0; i < CPT; ++i) {
        float v = elu1(acc[i] * rd[i] + bias[cc[i]]);
        if constexpr (SPLIT) {
            unsigned short hb = f2bf(v);
            outHi[(size_t)n * HCt + cc[i]] = hb;
            outLo[(size_t)n * HCt + cc[i]] = f2bf(v - bf2f(hb));
        } else {
            outF[(size_t)n * HCt + cc[i]] = v;
        }
    }
}

// ---------------- classifier: sigmoid(h3 @ Wc + bc) ----------------
__global__ void cls_kernel(const float* __restrict__ h, const float* __restrict__ Wc,
                           const float* __restrict__ bc, float* __restrict__ out) {
    int n = blockIdx.x * blockDim.x + threadIdx.x;
    if (n >= N_NODES) return;
    const float* hp = h + (size_t)n * 64;
    float s = bc[0];
#pragma unroll
    for (int k = 0; k < 64; k += 4) {
        float4 hv = *(const float4*)(hp + k);
        float4 wv = *(const float4*)(Wc + k);
        s += hv.x * wv.x + hv.y * wv.y + hv.z * wv.z + hv.w * wv.w;
    }
    out[n] = 1.f / (1.f + __expf(-s));
}

extern "C" void kernel_launch(void* const* d_in, const int* in_sizes, int n_in,
                              void* d_out, int out_size, void* d_ws, size_t ws_size,
                              hipStream_t stream) {
    const float* x   = (const float*)d_in[0];
    const int*   ei  = (const int*)d_in[1];
    const int* src_row = ei;
    const int* dst_row = ei + N_EDGES;
    const float* W1  = (const float*)d_in[2];
    const float* as1 = (const float*)d_in[3];
    const float* ad1 = (const float*)d_in[4];
    const float* b1  = (const float*)d_in[5];
    const float* W2  = (const float*)d_in[6];
    const float* as2 = (const float*)d_in[7];
    const float* ad2 = (const float*)d_in[8];
    const float* b2  = (const float*)d_in[9];
    const float* W3  = (const float*)d_in[10];
    const float* as3 = (const float*)d_in[11];
    const float* ad3 = (const float*)d_in[12];
    const float* b3  = (const float*)d_in[13];
    const float* Wc  = (const float*)d_in[14];
    const float* bc  = (const float*)d_in[15];

    char* w = (char*)d_ws;
    auto alloc = [&](size_t bytes) -> void* {
        void* ptr = (void*)w;
        w += (bytes + 255) & ~(size_t)255;
        return ptr;
    };
    int*   deg    = (int*)alloc((size_t)N_NODES * 4);
    int*   rowptr = (int*)alloc((size_t)(N_NODES + 1) * 4);
    int*   cursor = (int*)alloc((size_t)N_NODES * 4);
    int*   srcs   = (int*)alloc((size_t)E_TOT * 4);
    float* pbuf   = (float*)alloc((size_t)E_TOT * HEADS * 4);
    float* ssrc   = (float*)alloc((size_t)N_NODES * HEADS * 4);
    float* sdst   = (float*)alloc((size_t)N_NODES * HEADS * 4);
    float* rden   = (float*)alloc((size_t)N_NODES * HEADS * 4);
    float* hA     = (float*)alloc((size_t)N_NODES * HC * 4);          // fp32 h (GEMM out)
    unsigned short* ghi = (unsigned short*)alloc((size_t)N_NODES * HC * 2);  // agg out hi
    unsigned short* glo = (unsigned short*)alloc((size_t)N_NODES * HC * 2);  // agg out lo
    unsigned short* w2thi = (unsigned short*)alloc((size_t)512 * 512 * 2);
    unsigned short* w2tlo = (unsigned short*)alloc((size_t)512 * 512 * 2);
    unsigned short* w3thi = (unsigned short*)alloc((size_t)64 * 512 * 2);
    unsigned short* w3tlo = (unsigned short*)alloc((size_t)64 * 512 * 2);
    float* g3 = (float*)ghi;  // layer-3 agg out (fp32, 12.8MB) aliases ghi (free by then)

    hipMemsetAsync(deg, 0, (size_t)N_NODES * 4, stream);

    const int EB = (E_TOT + 255) / 256;
    hist_kernel<<<EB, 256, 0, stream>>>(dst_row, deg);
    scan_kernel<<<1, 1024, 0, stream>>>(deg, rowptr, cursor);
    scatter_kernel<<<EB, 256, 0, stream>>>(src_row, dst_row, cursor, srcs);

    // weight transpose+split (tiny; once per call)
    wsplit_kernel<512><<<(512 * 512 + 255) / 256, 256, 0, stream>>>(W2, w2thi, w2tlo);
    wsplit_kernel<64><<<(512 * 64 + 255) / 256, 256, 0, stream>>>(W3, w3thi, w3tlo);

    const int NHB = (N_NODES * HEADS + 255) / 256;
    const int NB  = (N_NODES + 255) / 256;
    const int MB  = (N_NODES + 127) / 128;  // 391

    // ---- layer 1: x[N,5] -> hA[N,512] -> attn -> ghi/glo (split bf16) ----
    gemm5_kernel<<<(N_NODES * HC + 255) / 256, 256, 0, stream>>>(x, W1, hA);
    score_kernel<8, 64><<<NHB, 256, 0, stream>>>(hA, as1, ad1, ssrc, sdst);
    softmax_kernel<8><<<NHB, 256, 0, stream>>>(rowptr, srcs, ssrc, sdst, pbuf, rden);
    agg_kernel<8, 64, 256, true><<<N_NODES, 256, 0, stream>>>(hA, pbuf, rowptr, srcs, rden, b1,
                                                              nullptr, ghi, glo);

    // ---- layer 2: g1 @ W2 (split-bf16 MFMA) -> hA -> attn -> ghi/glo ----
    gemm_mfma<128, 2, 2><<<dim3(4, MB), 256, 0, stream>>>(ghi, glo, w2thi, w2tlo, hA,
                                                          N_NODES, 512, 511);
    score_kernel<8, 64><<<NHB, 256, 0, stream>>>(hA, as2, ad2, ssrc, sdst);
    softmax_kernel<8><<<NHB, 256, 0, stream>>>(rowptr, srcs, ssrc, sdst, pbuf, rden);
    agg_kernel<8, 64, 256, true><<<N_NODES, 256, 0, stream>>>(hA, pbuf, rowptr, srcs, rden, b2,
                                                              nullptr, ghi, glo);

    // ---- layer 3: g2 @ W3 (split-bf16 MFMA) -> hA[N,64] -> attn (1 head) -> g3 ----
    gemm_mfma<64, 2, 1><<<dim3(1, MB), 128, 0, stream>>>(ghi, glo, w3thi, w3tlo, hA,
                                                         N_NODES, 64, 63);
    score_kernel<1, 64><<<NB, 256, 0, stream>>>(hA, as3, ad3, ssrc, sdst);
    softmax_kernel<1><<<NB, 256, 0, stream>>>(rowptr, srcs, ssrc, sdst, pbuf, rden);
    agg_kernel<1, 64, 64, false><<<N_NODES, 64, 0, stream>>>(hA, pbuf, rowptr, srcs, rden, b3,
                                                             g3, nullptr, nullptr);

    // ---- classifier ----
    cls_kernel<<<NB, 256, 0, stream>>>(g3, Wc, bc, (float*)d_out);
}

// Round 3
// 802.588 us; speedup vs baseline: 1.4642x; 1.0961x over previous
//
#include <hip/hip_runtime.h>
#include <hip/hip_bf16.h>
#include <math.h>

#define N_NODES 50000
#define N_EDGES 400000
#define E_TOT   (N_EDGES + N_NODES)   // self loops appended
#define HEADS   8
#define HID     64
#define HC      (HEADS * HID)         // 512

typedef __attribute__((ext_vector_type(8))) short bf16x8;  // 8 bf16 (4 VGPRs)
typedef __attribute__((ext_vector_type(4))) float f32x4;

__device__ __forceinline__ float elu1(float x) { return x > 0.f ? x : __expf(x) - 1.f; }

// round-to-nearest-even fp32 -> bf16 (raw ushort)
__device__ __forceinline__ unsigned short f2bf(float x) {
    unsigned u = __float_as_uint(x);
    unsigned r = (u + 0x7FFFu + ((u >> 16) & 1u)) >> 16;
    return (unsigned short)r;
}
__device__ __forceinline__ float bf2f(unsigned short h) {
    return __uint_as_float(((unsigned)h) << 16);
}

// ---------------- CSR build (by dst) ----------------
__global__ void hist_kernel(const int* __restrict__ dst, int* __restrict__ deg) {
    int e = blockIdx.x * blockDim.x + threadIdx.x;
    if (e >= E_TOT) return;
    int d = (e < N_EDGES) ? dst[e] : (e - N_EDGES);
    atomicAdd(&deg[d], 1);
}

__global__ __launch_bounds__(1024) void scan_kernel(const int* __restrict__ deg,
                                                    int* __restrict__ rowptr,
                                                    int* __restrict__ cursor) {
    __shared__ int part[1024];
    const int CH = (N_NODES + 1023) / 1024;  // 49
    int t = threadIdx.x;
    int base = t * CH;
    int sum = 0;
    for (int i = 0; i < CH; ++i) {
        int idx = base + i;
        if (idx < N_NODES) sum += deg[idx];
    }
    part[t] = sum;
    __syncthreads();
    for (int off = 1; off < 1024; off <<= 1) {
        int v = part[t];
        int add = (t >= off) ? part[t - off] : 0;
        __syncthreads();
        part[t] = v + add;
        __syncthreads();
    }
    int run = part[t] - sum;  // exclusive prefix of this chunk
    for (int i = 0; i < CH; ++i) {
        int idx = base + i;
        if (idx < N_NODES) {
            rowptr[idx] = run;
            cursor[idx] = run;
            run += deg[idx];
        }
    }
    if (t == 1023) rowptr[N_NODES] = part[1023];
}

__global__ void scatter_kernel(const int* __restrict__ srcrow, const int* __restrict__ dstrow,
                               int* __restrict__ cursor, int* __restrict__ src_sorted) {
    int e = blockIdx.x * blockDim.x + threadIdx.x;
    if (e >= E_TOT) return;
    int s, d;
    if (e < N_EDGES) { s = srcrow[e]; d = dstrow[e]; }
    else             { s = d = e - N_EDGES; }
    int pos = atomicAdd(&cursor[d], 1);
    src_sorted[pos] = s;
}

// ---------------- Layer 1 GEMM: [N,5] @ [5,512] -> bf16 h ----------------
__global__ void gemm5_kernel(const float* __restrict__ x, const float* __restrict__ W,
                             unsigned short* __restrict__ h) {
    int gid = blockIdx.x * blockDim.x + threadIdx.x;
    if (gid >= N_NODES * HC) return;
    int n = gid >> 9, c = gid & 511;
    const float* xr = x + n * 5;
    float acc = xr[0] * W[c] + xr[1] * W[512 + c] + xr[2] * W[1024 + c] +
                xr[3] * W[1536 + c] + xr[4] * W[2048 + c];
    h[gid] = f2bf(acc);
}

// ---------------- W -> W^T split (hi/lo bf16): W[512][NCOL] -> Wt[NCOL][512] ----------------
template <int NCOL>
__global__ void wsplit_kernel(const float* __restrict__ W, unsigned short* __restrict__ hi,
                              unsigned short* __restrict__ lo) {
    int idx = blockIdx.x * 256 + threadIdx.x;
    if (idx >= 512 * NCOL) return;
    int k = idx / NCOL, n = idx % NCOL;
    float v = W[idx];
    unsigned short h = f2bf(v);
    unsigned short l = f2bf(v - bf2f(h));
    hi[(size_t)n * 512 + k] = h;
    lo[(size_t)n * 512 + k] = l;
}

// ---------------- split-bf16 MFMA GEMM ----------------
// A (hi/lo): [M][512] bf16 row-major. B (hi/lo): [Ncols][512] bf16 (W^T). C: [M][Nout] bf16.
// LDS tile: per row 64B (32 bf16 of K-window); 16B-slot p holds k-chunk g = p ^ ((row>>1)&3)
// (XOR swizzle via pre-swizzled global source + matching swizzled ds_read; rule #21).
template <int ROWS, int NW>
__device__ __forceinline__ void stage_tile(const unsigned short* __restrict__ src, int row0,
                                           int maxRow, int k0, char* lds, int wave, int lane) {
    constexpr int CHUNKS = ROWS / 16;  // 1KB chunks (16 rows x 64B)
    for (int c = wave; c < CHUNKS; c += NW) {
        int r = c * 16 + (lane >> 2);
        int p = lane & 3;
        int g = p ^ ((r >> 1) & 3);
        int gr = row0 + r;
        if (gr > maxRow) gr = maxRow;  // tail clamp; result write-guarded
        const unsigned short* gp = src + (size_t)gr * 512 + k0 + g * 8;
        __builtin_amdgcn_global_load_lds((const __attribute__((address_space(1))) void*)gp,
                                         (__attribute__((address_space(3))) void*)(lds + c * 1024),
                                         16, 0, 0);
    }
}

template <int BN, int WM, int WN>
__global__ __launch_bounds__(WM * WN * 64) void gemm_mfma(
    const unsigned short* __restrict__ Ahi, const unsigned short* __restrict__ Alo,
    const unsigned short* __restrict__ Bhi, const unsigned short* __restrict__ Blo,
    unsigned short* __restrict__ C, int M, int Nout, int maxRowB) {
    constexpr int BM = 128;
    constexpr int NW = WM * WN;
    __shared__ __attribute__((aligned(16))) char ldsAhi[BM * 64];
    __shared__ __attribute__((aligned(16))) char ldsAlo[BM * 64];
    __shared__ __attribute__((aligned(16))) char ldsBhi[BN * 64];
    __shared__ __attribute__((aligned(16))) char ldsBlo[BN * 64];
    const int t = threadIdx.x, lane = t & 63, wave = t >> 6;
    const int wr = wave / WN, wc = wave % WN;
    const int m0 = blockIdx.y * BM, n0 = blockIdx.x * BN;

    int offA[4], offB[4];
#pragma unroll
    for (int s = 0; s < 4; ++s) {
        int rA = wr * 64 + s * 16 + (lane & 15);
        offA[s] = rA * 64 + ((((lane >> 4) ^ ((rA >> 1) & 3))) << 4);
        int rB = wc * 64 + s * 16 + (lane & 15);
        offB[s] = rB * 64 + ((((lane >> 4) ^ ((rB >> 1) & 3))) << 4);
    }

    f32x4 acc[4][4] = {};

    for (int k0 = 0; k0 < 512; k0 += 32) {
        stage_tile<BM, NW>(Ahi, m0, M - 1, k0, ldsAhi, wave, lane);
        stage_tile<BM, NW>(Alo, m0, M - 1, k0, ldsAlo, wave, lane);
        stage_tile<BN, NW>(Bhi, n0, maxRowB, k0, ldsBhi, wave, lane);
        stage_tile<BN, NW>(Blo, n0, maxRowB, k0, ldsBlo, wave, lane);
        __syncthreads();

        bf16x8 ah[4], al[4], bh[4], bl[4];
#pragma unroll
        for (int s = 0; s < 4; ++s) {
            ah[s] = *(const bf16x8*)(ldsAhi + offA[s]);
            al[s] = *(const bf16x8*)(ldsAlo + offA[s]);
            bh[s] = *(const bf16x8*)(ldsBhi + offB[s]);
            bl[s] = *(const bf16x8*)(ldsBlo + offB[s]);
        }
#pragma unroll
        for (int i = 0; i < 4; ++i)
#pragma unroll
            for (int j = 0; j < 4; ++j) {
                acc[i][j] = __builtin_amdgcn_mfma_f32_16x16x32_bf16(ah[i], bh[j], acc[i][j], 0, 0, 0);
                acc[i][j] = __builtin_amdgcn_mfma_f32_16x16x32_bf16(ah[i], bl[j], acc[i][j], 0, 0, 0);
                acc[i][j] = __builtin_amdgcn_mfma_f32_16x16x32_bf16(al[i], bh[j], acc[i][j], 0, 0, 0);
            }
        __syncthreads();
    }

    // C/D layout (m89-verified): col = lane&15, row = (lane>>4)*4 + reg
#pragma unroll
    for (int i = 0; i < 4; ++i) {
        int row = m0 + wr * 64 + i * 16 + ((lane >> 4) << 2);
#pragma unroll
        for (int j = 0; j < 4; ++j) {
            int col = n0 + wc * 64 + j * 16 + (lane & 15);
            f32x4 v = acc[i][j];
#pragma unroll
            for (int r = 0; r < 4; ++r) {
                if (row + r < M) C[(size_t)(row + r) * Nout + col] = f2bf(v[r]);
            }
        }
    }
}

// ---------------- attention scores from bf16 h: s_src/s_dst [N,H] ----------------
template <int H>
__global__ void score_kernel(const unsigned short* __restrict__ h,
                             const float* __restrict__ a_src, const float* __restrict__ a_dst,
                             float* __restrict__ ssrc, float* __restrict__ sdst) {
    int gid = blockIdx.x * blockDim.x + threadIdx.x;
    if (gid >= N_NODES * H) return;
    int n = gid / H, hh = gid % H;
    const unsigned short* hp = h + (size_t)n * (H * 64) + hh * 64;
    const float* asp = a_src + hh * 64;
    const float* adp = a_dst + hh * 64;
    float s1 = 0.f, s2 = 0.f;
#pragma unroll
    for (int k = 0; k < 64; k += 8) {
        uint4 hv = *(const uint4*)(hp + k);
        const unsigned u[4] = {hv.x, hv.y, hv.z, hv.w};
#pragma unroll
        for (int q = 0; q < 4; ++q) {
            float f0 = bf2f((unsigned short)(u[q] & 0xffff));
            float f1 = bf2f((unsigned short)(u[q] >> 16));
            s1 = fmaf(f0, asp[k + 2 * q], fmaf(f1, asp[k + 2 * q + 1], s1));
            s2 = fmaf(f0, adp[k + 2 * q], fmaf(f1, adp[k + 2 * q + 1], s2));
        }
    }
    ssrc[gid] = s1;
    sdst[gid] = s2;
}

// ---------------- per-(dst,head) softmax: unnormalized p and 1/denom ----------------
template <int H>
__global__ void softmax_kernel(const int* __restrict__ rowptr, const int* __restrict__ srcs,
                               const float* __restrict__ ssrc, const float* __restrict__ sdst,
                               float* __restrict__ p, float* __restrict__ rden) {
    int gid = blockIdx.x * blockDim.x + threadIdx.x;
    if (gid >= N_NODES * H) return;
    int n = gid / H, hh = gid % H;
    int lo = rowptr[n], hi = rowptr[n + 1];
    float sd = sdst[gid];
    float mx = -3.4e38f;
    for (int j = lo; j < hi; ++j) {
        float v = ssrc[srcs[j] * H + hh] + sd;
        v = v > 0.f ? v : 0.2f * v;
        mx = fmaxf(mx, v);
    }
    float sum = 0.f;
    for (int j = lo; j < hi; ++j) {
        float v = ssrc[srcs[j] * H + hh] + sd;
        v = v > 0.f ? v : 0.2f * v;
        float pe = __expf(v - mx);
        p[(size_t)j * H + hh] = pe;
        sum += pe;
    }
    rden[gid] = 1.f / (sum + 1e-16f);
}

// ---------------- gather-aggregate (8 heads, 512 ch, bf16 h) + bias + ELU + hi/lo split out ----
__global__ __launch_bounds__(256) void agg8_kernel(const unsigned short* __restrict__ h,
                                                   const float* __restrict__ p,
                                                   const int* __restrict__ rowptr,
                                                   const int* __restrict__ srcs,
                                                   const float* __restrict__ rden,
                                                   const float* __restrict__ bias,
                                                   unsigned short* __restrict__ outHi,
                                                   unsigned short* __restrict__ outLo) {
    int n = blockIdx.x;
    int t = threadIdx.x;           // pair index: channels 2t, 2t+1 (same head: 2t even)
    int hh = t >> 5;               // (2t)/64
    int lo = rowptr[n], hi = rowptr[n + 1];
    float rd = rden[n * 8 + hh];
    float a0 = 0.f, a1 = 0.f;
    for (int j = lo; j < hi; ++j) {
        int s = srcs[j];
        unsigned v = *(const unsigned*)(h + (size_t)s * 512 + 2 * t);
        float pj = p[(size_t)j * 8 + hh];
        a0 = fmaf(pj, bf2f((unsigned short)(v & 0xffff)), a0);
        a1 = fmaf(pj, bf2f((unsigned short)(v >> 16)), a1);
    }
    float2 bv = *(const float2*)(bias + 2 * t);
    float v0 = elu1(a0 * rd + bv.x);
    float v1 = elu1(a1 * rd + bv.y);
    unsigned short h0 = f2bf(v0), h1 = f2bf(v1);
    unsigned hiPack = (unsigned)h0 | ((unsigned)h1 << 16);
    unsigned loPack = (unsigned)f2bf(v0 - bf2f(h0)) | ((unsigned)f2bf(v1 - bf2f(h1)) << 16);
    *(unsigned*)(outHi + (size_t)n * 512 + 2 * t) = hiPack;
    *(unsigned*)(outLo + (size_t)n * 512 + 2 * t) = loPack;
}

// ---------------- gather-aggregate (1 head, 64 ch, bf16 h) + bias + ELU -> fp32 ----------------
__global__ __launch_bounds__(64) void agg1_kernel(const unsigned short* __restrict__ h,
                                                  const float* __restrict__ p,
                                                  const int* __restrict__ rowptr,
                                                  const int* __restrict__ srcs,
                                                  const float* __restrict__ rden,
                                                  const float* __restrict__ bias,
                                                  float* __restrict__ out) {
    int n = blockIdx.x;
    int t = threadIdx.x;
    int lo = rowptr[n], hi = rowptr[n + 1];
    float rd = rden[n];
    float acc = 0.f;
    for (int j = lo; j < hi; ++j) {
        int s = srcs[j];
        acc = fmaf(p[j], bf2f(h[(size_t)s * 64 + t]), acc);
    }
    out[(size_t)n * 64 + t] = elu1(acc * rd + bias[t]);
}

// ---------------- classifier: sigmoid(h3 @ Wc + bc) ----------------
__global__ void cls_kernel(const float* __restrict__ h, const float* __restrict__ Wc,
                           const float* __restrict__ bc, float* __restrict__ out) {
    int n = blockIdx.x * blockDim.x + threadIdx.x;
    if (n >= N_NODES) return;
    const float* hp = h + (size_t)n * 64;
    float s = bc[0];
#pragma unroll
    for (int k = 0; k < 64; k += 4) {
        float4 hv = *(const float4*)(hp + k);
        float4 wv = *(const float4*)(Wc + k);
        s += hv.x * wv.x + hv.y * wv.y + hv.z * wv.z + hv.w * wv.w;
    }
    out[n] = 1.f / (1.f + __expf(-s));
}

extern "C" void kernel_launch(void* const* d_in, const int* in_sizes, int n_in,
                              void* d_out, int out_size, void* d_ws, size_t ws_size,
                              hipStream_t stream) {
    const float* x   = (const float*)d_in[0];
    const int*   ei  = (const int*)d_in[1];
    const int* src_row = ei;
    const int* dst_row = ei + N_EDGES;
    const float* W1  = (const float*)d_in[2];
    const float* as1 = (const float*)d_in[3];
    const float* ad1 = (const float*)d_in[4];
    const float* b1  = (const float*)d_in[5];
    const float* W2  = (const float*)d_in[6];
    const float* as2 = (const float*)d_in[7];
    const float* ad2 = (const float*)d_in[8];
    const float* b2  = (const float*)d_in[9];
    const float* W3  = (const float*)d_in[10];
    const float* as3 = (const float*)d_in[11];
    const float* ad3 = (const float*)d_in[12];
    const float* b3  = (const float*)d_in[13];
    const float* Wc  = (const float*)d_in[14];
    const float* bc  = (const float*)d_in[15];

    char* w = (char*)d_ws;
    auto alloc = [&](size_t bytes) -> void* {
        void* ptr = (void*)w;
        w += (bytes + 255) & ~(size_t)255;
        return ptr;
    };
    int*   deg    = (int*)alloc((size_t)N_NODES * 4);
    int*   rowptr = (int*)alloc((size_t)(N_NODES + 1) * 4);
    int*   cursor = (int*)alloc((size_t)N_NODES * 4);
    int*   srcs   = (int*)alloc((size_t)E_TOT * 4);
    float* pbuf   = (float*)alloc((size_t)E_TOT * HEADS * 4);
    float* ssrc   = (float*)alloc((size_t)N_NODES * HEADS * 4);
    float* sdst   = (float*)alloc((size_t)N_NODES * HEADS * 4);
    float* rden   = (float*)alloc((size_t)N_NODES * HEADS * 4);
    unsigned short* hbf = (unsigned short*)alloc((size_t)N_NODES * HC * 2);  // bf16 h (GEMM out)
    unsigned short* ghi = (unsigned short*)alloc((size_t)N_NODES * HC * 2);  // agg out hi
    unsigned short* glo = (unsigned short*)alloc((size_t)N_NODES * HC * 2);  // agg out lo
    unsigned short* w2thi = (unsigned short*)alloc((size_t)512 * 512 * 2);
    unsigned short* w2tlo = (unsigned short*)alloc((size_t)512 * 512 * 2);
    unsigned short* w3thi = (unsigned short*)alloc((size_t)64 * 512 * 2);
    unsigned short* w3tlo = (unsigned short*)alloc((size_t)64 * 512 * 2);
    float* g3 = (float*)ghi;  // layer-3 agg out (fp32, 12.8MB) aliases ghi (free by then)

    hipMemsetAsync(deg, 0, (size_t)N_NODES * 4, stream);

    const int EB = (E_TOT + 255) / 256;
    hist_kernel<<<EB, 256, 0, stream>>>(dst_row, deg);
    scan_kernel<<<1, 1024, 0, stream>>>(deg, rowptr, cursor);
    scatter_kernel<<<EB, 256, 0, stream>>>(src_row, dst_row, cursor, srcs);

    // weight transpose+split (tiny; once per call)
    wsplit_kernel<512><<<(512 * 512 + 255) / 256, 256, 0, stream>>>(W2, w2thi, w2tlo);
    wsplit_kernel<64><<<(512 * 64 + 255) / 256, 256, 0, stream>>>(W3, w3thi, w3tlo);

    const int NHB = (N_NODES * HEADS + 255) / 256;
    const int NB  = (N_NODES + 255) / 256;
    const int MB  = (N_NODES + 127) / 128;  // 391

    // ---- layer 1: x[N,5] -> hbf[N,512] -> attn -> ghi/glo ----
    gemm5_kernel<<<(N_NODES * HC + 255) / 256, 256, 0, stream>>>(x, W1, hbf);
    score_kernel<8><<<NHB, 256, 0, stream>>>(hbf, as1, ad1, ssrc, sdst);
    softmax_kernel<8><<<NHB, 256, 0, stream>>>(rowptr, srcs, ssrc, sdst, pbuf, rden);
    agg8_kernel<<<N_NODES, 256, 0, stream>>>(hbf, pbuf, rowptr, srcs, rden, b1, ghi, glo);

    // ---- layer 2: g1 @ W2 (split-bf16 MFMA) -> hbf -> attn -> ghi/glo ----
    gemm_mfma<128, 2, 2><<<dim3(4, MB), 256, 0, stream>>>(ghi, glo, w2thi, w2tlo, hbf,
                                                          N_NODES, 512, 511);
    score_kernel<8><<<NHB, 256, 0, stream>>>(hbf, as2, ad2, ssrc, sdst);
    softmax_kernel<8><<<NHB, 256, 0, stream>>>(rowptr, srcs, ssrc, sdst, pbuf, rden);
    agg8_kernel<<<N_NODES, 256, 0, stream>>>(hbf, pbuf, rowptr, srcs, rden, b2, ghi, glo);

    // ---- layer 3: g2 @ W3 (split-bf16 MFMA) -> hbf[N,64] -> attn (1 head) -> g3 ----
    gemm_mfma<64, 2, 1><<<dim3(1, MB), 128, 0, stream>>>(ghi, glo, w3thi, w3tlo, hbf,
                                                         N_NODES, 64, 63);
    score_kernel<1><<<NB, 256, 0, stream>>>(hbf, as3, ad3, ssrc, sdst);
    softmax_kernel<1><<<NB, 256, 0, stream>>>(rowptr, srcs, ssrc, sdst, pbuf, rden);
    agg1_kernel<<<N_NODES, 64, 0, stream>>>(hbf, pbuf, rowptr, srcs, rden, b3, g3);

    // ---- classifier ----
    cls_kernel<<<NB, 256, 0, stream>>>(g3, Wc, bc, (float*)d_out);
}

// Round 4
// 687.286 us; speedup vs baseline: 1.7099x; 1.1678x over previous
//
#include <hip/hip_runtime.h>
#include <hip/hip_bf16.h>
#include <math.h>

#define N_NODES 50000
#define N_EDGES 400000
#define E_TOT   (N_EDGES + N_NODES)   // self loops appended
#define HEADS   8
#define HID     64
#define HC      (HEADS * HID)         // 512
#define NBLK    ((N_NODES + 255) / 256)  // 196 scan blocks

typedef __attribute__((ext_vector_type(8))) short bf16x8;  // 8 bf16 (4 VGPRs)
typedef __attribute__((ext_vector_type(4))) float f32x4;

__device__ __forceinline__ float elu1(float x) { return x > 0.f ? x : __expf(x) - 1.f; }

// round-to-nearest-even fp32 -> bf16 (raw ushort)
__device__ __forceinline__ unsigned short f2bf(float x) {
    unsigned u = __float_as_uint(x);
    unsigned r = (u + 0x7FFFu + ((u >> 16) & 1u)) >> 16;
    return (unsigned short)r;
}
__device__ __forceinline__ float bf2f(unsigned short h) {
    return __uint_as_float(((unsigned)h) << 16);
}

// ---------------- CSR build (by dst) ----------------
__global__ void hist_kernel(const int* __restrict__ dst, int* __restrict__ deg) {
    int e = blockIdx.x * blockDim.x + threadIdx.x;
    if (e >= E_TOT) return;
    int d = (e < N_EDGES) ? dst[e] : (e - N_EDGES);
    atomicAdd(&deg[d], 1);
}

// 1) per-block sums of deg
__global__ __launch_bounds__(256) void deg_partial_kernel(const int* __restrict__ deg,
                                                          int* __restrict__ psum) {
    __shared__ int sm[256];
    int t = threadIdx.x;
    int idx = blockIdx.x * 256 + t;
    int v = (idx < N_NODES) ? deg[idx] : 0;
    sm[t] = v;
    __syncthreads();
    for (int off = 128; off >= 1; off >>= 1) {
        if (t < off) sm[t] += sm[t + off];
        __syncthreads();
    }
    if (t == 0) psum[blockIdx.x] = sm[0];
}

// 2) exclusive scan of the NBLK block sums (single block)
__global__ __launch_bounds__(256) void scan_partial_kernel(int* __restrict__ psum) {
    __shared__ int sm[256];
    int t = threadIdx.x;
    int v = (t < NBLK) ? psum[t] : 0;
    sm[t] = v;
    __syncthreads();
    for (int off = 1; off < 256; off <<= 1) {
        int add = (t >= off) ? sm[t - off] : 0;
        __syncthreads();
        sm[t] += add;
        __syncthreads();
    }
    if (t < NBLK) psum[t] = sm[t] - v;  // exclusive
}

// 3) per-chunk exclusive scan + block offset -> rowptr, cursor
__global__ __launch_bounds__(256) void rowptr_kernel(const int* __restrict__ deg,
                                                     const int* __restrict__ psum,
                                                     int* __restrict__ rowptr,
                                                     int* __restrict__ cursor) {
    __shared__ int sm[256];
    int t = threadIdx.x;
    int idx = blockIdx.x * 256 + t;
    int v = (idx < N_NODES) ? deg[idx] : 0;
    sm[t] = v;
    __syncthreads();
    for (int off = 1; off < 256; off <<= 1) {
        int add = (t >= off) ? sm[t - off] : 0;
        __syncthreads();
        sm[t] += add;
        __syncthreads();
    }
    if (idx < N_NODES) {
        int r = psum[blockIdx.x] + sm[t] - v;  // exclusive
        rowptr[idx] = r;
        cursor[idx] = r;
    }
    if (idx == 0) rowptr[N_NODES] = E_TOT;
}

__global__ void scatter_kernel(const int* __restrict__ srcrow, const int* __restrict__ dstrow,
                               int* __restrict__ cursor, int* __restrict__ src_sorted) {
    int e = blockIdx.x * blockDim.x + threadIdx.x;
    if (e >= E_TOT) return;
    int s, d;
    if (e < N_EDGES) { s = srcrow[e]; d = dstrow[e]; }
    else             { s = d = e - N_EDGES; }
    int pos = atomicAdd(&cursor[d], 1);
    src_sorted[pos] = s;
}

// ---------------- Layer 1 GEMM: [N,5] @ [5,512] -> bf16 h ----------------
__global__ void gemm5_kernel(const float* __restrict__ x, const float* __restrict__ W,
                             unsigned short* __restrict__ h) {
    int gid = blockIdx.x * blockDim.x + threadIdx.x;
    if (gid >= N_NODES * HC) return;
    int n = gid >> 9, c = gid & 511;
    const float* xr = x + n * 5;
    float acc = xr[0] * W[c] + xr[1] * W[512 + c] + xr[2] * W[1024 + c] +
                xr[3] * W[1536 + c] + xr[4] * W[2048 + c];
    h[gid] = f2bf(acc);
}

// ---------------- W -> W^T split (hi/lo bf16): W[512][NCOL] -> Wt[NCOL][512] ----------------
template <int NCOL>
__global__ void wsplit_kernel(const float* __restrict__ W, unsigned short* __restrict__ hi,
                              unsigned short* __restrict__ lo) {
    int idx = blockIdx.x * 256 + threadIdx.x;
    if (idx >= 512 * NCOL) return;
    int k = idx / NCOL, n = idx % NCOL;
    float v = W[idx];
    unsigned short h = f2bf(v);
    unsigned short l = f2bf(v - bf2f(h));
    hi[(size_t)n * 512 + k] = h;
    lo[(size_t)n * 512 + k] = l;
}

// ---------------- split-bf16 MFMA GEMM ----------------
// A (hi/lo): [M][512] bf16 row-major. B (hi/lo): [Ncols][512] bf16 (W^T). C: [M][Nout] bf16.
// LDS tile: per row 64B (32 bf16 of K-window); 16B-slot p holds k-chunk g = p ^ ((row>>1)&3)
// (XOR swizzle via pre-swizzled global source + matching swizzled ds_read; rule #21).
template <int ROWS, int NW>
__device__ __forceinline__ void stage_tile(const unsigned short* __restrict__ src, int row0,
                                           int maxRow, int k0, char* lds, int wave, int lane) {
    constexpr int CHUNKS = ROWS / 16;  // 1KB chunks (16 rows x 64B)
    for (int c = wave; c < CHUNKS; c += NW) {
        int r = c * 16 + (lane >> 2);
        int p = lane & 3;
        int g = p ^ ((r >> 1) & 3);
        int gr = row0 + r;
        if (gr > maxRow) gr = maxRow;  // tail clamp; result write-guarded
        const unsigned short* gp = src + (size_t)gr * 512 + k0 + g * 8;
        __builtin_amdgcn_global_load_lds((const __attribute__((address_space(1))) void*)gp,
                                         (__attribute__((address_space(3))) void*)(lds + c * 1024),
                                         16, 0, 0);
    }
}

template <int BN, int WM, int WN>
__global__ __launch_bounds__(WM * WN * 64) void gemm_mfma(
    const unsigned short* __restrict__ Ahi, const unsigned short* __restrict__ Alo,
    const unsigned short* __restrict__ Bhi, const unsigned short* __restrict__ Blo,
    unsigned short* __restrict__ C, int M, int Nout, int maxRowB) {
    constexpr int BM = 128;
    constexpr int NW = WM * WN;
    __shared__ __attribute__((aligned(16))) char ldsAhi[BM * 64];
    __shared__ __attribute__((aligned(16))) char ldsAlo[BM * 64];
    __shared__ __attribute__((aligned(16))) char ldsBhi[BN * 64];
    __shared__ __attribute__((aligned(16))) char ldsBlo[BN * 64];
    const int t = threadIdx.x, lane = t & 63, wave = t >> 6;
    const int wr = wave / WN, wc = wave % WN;
    const int m0 = blockIdx.y * BM, n0 = blockIdx.x * BN;

    int offA[4], offB[4];
#pragma unroll
    for (int s = 0; s < 4; ++s) {
        int rA = wr * 64 + s * 16 + (lane & 15);
        offA[s] = rA * 64 + ((((lane >> 4) ^ ((rA >> 1) & 3))) << 4);
        int rB = wc * 64 + s * 16 + (lane & 15);
        offB[s] = rB * 64 + ((((lane >> 4) ^ ((rB >> 1) & 3))) << 4);
    }

    f32x4 acc[4][4] = {};

    for (int k0 = 0; k0 < 512; k0 += 32) {
        stage_tile<BM, NW>(Ahi, m0, M - 1, k0, ldsAhi, wave, lane);
        stage_tile<BM, NW>(Alo, m0, M - 1, k0, ldsAlo, wave, lane);
        stage_tile<BN, NW>(Bhi, n0, maxRowB, k0, ldsBhi, wave, lane);
        stage_tile<BN, NW>(Blo, n0, maxRowB, k0, ldsBlo, wave, lane);
        __syncthreads();

        bf16x8 ah[4], al[4], bh[4], bl[4];
#pragma unroll
        for (int s = 0; s < 4; ++s) {
            ah[s] = *(const bf16x8*)(ldsAhi + offA[s]);
            al[s] = *(const bf16x8*)(ldsAlo + offA[s]);
            bh[s] = *(const bf16x8*)(ldsBhi + offB[s]);
            bl[s] = *(const bf16x8*)(ldsBlo + offB[s]);
        }
#pragma unroll
        for (int i = 0; i < 4; ++i)
#pragma unroll
            for (int j = 0; j < 4; ++j) {
                acc[i][j] = __builtin_amdgcn_mfma_f32_16x16x32_bf16(ah[i], bh[j], acc[i][j], 0, 0, 0);
                acc[i][j] = __builtin_amdgcn_mfma_f32_16x16x32_bf16(ah[i], bl[j], acc[i][j], 0, 0, 0);
                acc[i][j] = __builtin_amdgcn_mfma_f32_16x16x32_bf16(al[i], bh[j], acc[i][j], 0, 0, 0);
            }
        __syncthreads();
    }

    // C/D layout (m89-verified): col = lane&15, row = (lane>>4)*4 + reg
#pragma unroll
    for (int i = 0; i < 4; ++i) {
        int row = m0 + wr * 64 + i * 16 + ((lane >> 4) << 2);
#pragma unroll
        for (int j = 0; j < 4; ++j) {
            int col = n0 + wc * 64 + j * 16 + (lane & 15);
            f32x4 v = acc[i][j];
#pragma unroll
            for (int r = 0; r < 4; ++r) {
                if (row + r < M) C[(size_t)(row + r) * Nout + col] = f2bf(v[r]);
            }
        }
    }
}

// ---------------- attention scores from bf16 h: s_src/s_dst [N,H] ----------------
template <int H>
__global__ void score_kernel(const unsigned short* __restrict__ h,
                             const float* __restrict__ a_src, const float* __restrict__ a_dst,
                             float* __restrict__ ssrc, float* __restrict__ sdst) {
    int gid = blockIdx.x * blockDim.x + threadIdx.x;
    if (gid >= N_NODES * H) return;
    int n = gid / H, hh = gid % H;
    const unsigned short* hp = h + (size_t)n * (H * 64) + hh * 64;
    const float* asp = a_src + hh * 64;
    const float* adp = a_dst + hh * 64;
    float s1 = 0.f, s2 = 0.f;
#pragma unroll
    for (int k = 0; k < 64; k += 8) {
        uint4 hv = *(const uint4*)(hp + k);
        const unsigned u[4] = {hv.x, hv.y, hv.z, hv.w};
#pragma unroll
        for (int q = 0; q < 4; ++q) {
            float f0 = bf2f((unsigned short)(u[q] & 0xffff));
            float f1 = bf2f((unsigned short)(u[q] >> 16));
            s1 = fmaf(f0, asp[k + 2 * q], fmaf(f1, asp[k + 2 * q + 1], s1));
            s2 = fmaf(f0, adp[k + 2 * q], fmaf(f1, adp[k + 2 * q + 1], s2));
        }
    }
    ssrc[gid] = s1;
    sdst[gid] = s2;
}

// ---------------- per-(dst,head) softmax: unnormalized p and 1/denom ----------------
template <int H>
__global__ void softmax_kernel(const int* __restrict__ rowptr, const int* __restrict__ srcs,
                               const float* __restrict__ ssrc, const float* __restrict__ sdst,
                               float* __restrict__ p, float* __restrict__ rden) {
    int gid = blockIdx.x * blockDim.x + threadIdx.x;
    if (gid >= N_NODES * H) return;
    int n = gid / H, hh = gid % H;
    int lo = rowptr[n], hi = rowptr[n + 1];
    float sd = sdst[gid];
    float mx = -3.4e38f;
    for (int j = lo; j < hi; ++j) {
        float v = ssrc[srcs[j] * H + hh] + sd;
        v = v > 0.f ? v : 0.2f * v;
        mx = fmaxf(mx, v);
    }
    float sum = 0.f;
    for (int j = lo; j < hi; ++j) {
        float v = ssrc[srcs[j] * H + hh] + sd;
        v = v > 0.f ? v : 0.2f * v;
        float pe = __expf(v - mx);
        p[(size_t)j * H + hh] = pe;
        sum += pe;
    }
    rden[gid] = 1.f / (sum + 1e-16f);
}

// ---------------- gather-aggregate (8 heads, 512 ch, bf16 h) + bias + ELU + hi/lo split out ----
__global__ __launch_bounds__(256) void agg8_kernel(const unsigned short* __restrict__ h,
                                                   const float* __restrict__ p,
                                                   const int* __restrict__ rowptr,
                                                   const int* __restrict__ srcs,
                                                   const float* __restrict__ rden,
                                                   const float* __restrict__ bias,
                                                   unsigned short* __restrict__ outHi,
                                                   unsigned short* __restrict__ outLo) {
    int n = blockIdx.x;
    int t = threadIdx.x;           // pair index: channels 2t, 2t+1 (same head: 2t even)
    int hh = t >> 5;               // (2t)/64
    int lo = rowptr[n], hi = rowptr[n + 1];
    float rd = rden[n * 8 + hh];
    float a0 = 0.f, a1 = 0.f;
    for (int j = lo; j < hi; ++j) {
        int s = srcs[j];
        unsigned v = *(const unsigned*)(h + (size_t)s * 512 + 2 * t);
        float pj = p[(size_t)j * 8 + hh];
        a0 = fmaf(pj, bf2f((unsigned short)(v & 0xffff)), a0);
        a1 = fmaf(pj, bf2f((unsigned short)(v >> 16)), a1);
    }
    float2 bv = *(const float2*)(bias + 2 * t);
    float v0 = elu1(a0 * rd + bv.x);
    float v1 = elu1(a1 * rd + bv.y);
    unsigned short h0 = f2bf(v0), h1 = f2bf(v1);
    unsigned hiPack = (unsigned)h0 | ((unsigned)h1 << 16);
    unsigned loPack = (unsigned)f2bf(v0 - bf2f(h0)) | ((unsigned)f2bf(v1 - bf2f(h1)) << 16);
    *(unsigned*)(outHi + (size_t)n * 512 + 2 * t) = hiPack;
    *(unsigned*)(outLo + (size_t)n * 512 + 2 * t) = loPack;
}

// ---------------- gather-aggregate (1 head, 64 ch, bf16 h) + bias + ELU -> fp32 ----------------
__global__ __launch_bounds__(64) void agg1_kernel(const unsigned short* __restrict__ h,
                                                  const float* __restrict__ p,
                                                  const int* __restrict__ rowptr,
                                                  const int* __restrict__ srcs,
                                                  const float* __restrict__ rden,
                                                  const float* __restrict__ bias,
                                                  float* __restrict__ out) {
    int n = blockIdx.x;
    int t = threadIdx.x;
    int lo = rowptr[n], hi = rowptr[n + 1];
    float rd = rden[n];
    float acc = 0.f;
    for (int j = lo; j < hi; ++j) {
        int s = srcs[j];
        acc = fmaf(p[j], bf2f(h[(size_t)s * 64 + t]), acc);
    }
    out[(size_t)n * 64 + t] = elu1(acc * rd + bias[t]);
}

// ---------------- classifier: sigmoid(h3 @ Wc + bc) ----------------
__global__ void cls_kernel(const float* __restrict__ h, const float* __restrict__ Wc,
                           const float* __restrict__ bc, float* __restrict__ out) {
    int n = blockIdx.x * blockDim.x + threadIdx.x;
    if (n >= N_NODES) return;
    const float* hp = h + (size_t)n * 64;
    float s = bc[0];
#pragma unroll
    for (int k = 0; k < 64; k += 4) {
        float4 hv = *(const float4*)(hp + k);
        float4 wv = *(const float4*)(Wc + k);
        s += hv.x * wv.x + hv.y * wv.y + hv.z * wv.z + hv.w * wv.w;
    }
    out[n] = 1.f / (1.f + __expf(-s));
}

extern "C" void kernel_launch(void* const* d_in, const int* in_sizes, int n_in,
                              void* d_out, int out_size, void* d_ws, size_t ws_size,
                              hipStream_t stream) {
    const float* x   = (const float*)d_in[0];
    const int*   ei  = (const int*)d_in[1];
    const int* src_row = ei;
    const int* dst_row = ei + N_EDGES;
    const float* W1  = (const float*)d_in[2];
    const float* as1 = (const float*)d_in[3];
    const float* ad1 = (const float*)d_in[4];
    const float* b1  = (const float*)d_in[5];
    const float* W2  = (const float*)d_in[6];
    const float* as2 = (const float*)d_in[7];
    const float* ad2 = (const float*)d_in[8];
    const float* b2  = (const float*)d_in[9];
    const float* W3  = (const float*)d_in[10];
    const float* as3 = (const float*)d_in[11];
    const float* ad3 = (const float*)d_in[12];
    const float* b3  = (const float*)d_in[13];
    const float* Wc  = (const float*)d_in[14];
    const float* bc  = (const float*)d_in[15];

    char* w = (char*)d_ws;
    auto alloc = [&](size_t bytes) -> void* {
        void* ptr = (void*)w;
        w += (bytes + 255) & ~(size_t)255;
        return ptr;
    };
    int*   deg    = (int*)alloc((size_t)N_NODES * 4);
    int*   rowptr = (int*)alloc((size_t)(N_NODES + 1) * 4);
    int*   cursor = (int*)alloc((size_t)N_NODES * 4);
    int*   srcs   = (int*)alloc((size_t)E_TOT * 4);
    int*   psum   = (int*)alloc((size_t)NBLK * 4);
    float* pbuf   = (float*)alloc((size_t)E_TOT * HEADS * 4);
    float* ssrc   = (float*)alloc((size_t)N_NODES * HEADS * 4);
    float* sdst   = (float*)alloc((size_t)N_NODES * HEADS * 4);
    float* rden   = (float*)alloc((size_t)N_NODES * HEADS * 4);
    unsigned short* hbf = (unsigned short*)alloc((size_t)N_NODES * HC * 2);  // bf16 h (GEMM out)
    unsigned short* ghi = (unsigned short*)alloc((size_t)N_NODES * HC * 2);  // agg out hi
    unsigned short* glo = (unsigned short*)alloc((size_t)N_NODES * HC * 2);  // agg out lo
    unsigned short* w2thi = (unsigned short*)alloc((size_t)512 * 512 * 2);
    unsigned short* w2tlo = (unsigned short*)alloc((size_t)512 * 512 * 2);
    unsigned short* w3thi = (unsigned short*)alloc((size_t)64 * 512 * 2);
    unsigned short* w3tlo = (unsigned short*)alloc((size_t)64 * 512 * 2);
    float* g3 = (float*)ghi;  // layer-3 agg out (fp32, 12.8MB) aliases ghi (free by then)

    hipMemsetAsync(deg, 0, (size_t)N_NODES * 4, stream);

    const int EB = (E_TOT + 255) / 256;
    hist_kernel<<<EB, 256, 0, stream>>>(dst_row, deg);
    deg_partial_kernel<<<NBLK, 256, 0, stream>>>(deg, psum);
    scan_partial_kernel<<<1, 256, 0, stream>>>(psum);
    rowptr_kernel<<<NBLK, 256, 0, stream>>>(deg, psum, rowptr, cursor);
    scatter_kernel<<<EB, 256, 0, stream>>>(src_row, dst_row, cursor, srcs);

    // weight transpose+split (tiny; once per call)
    wsplit_kernel<512><<<(512 * 512 + 255) / 256, 256, 0, stream>>>(W2, w2thi, w2tlo);
    wsplit_kernel<64><<<(512 * 64 + 255) / 256, 256, 0, stream>>>(W3, w3thi, w3tlo);

    const int NHB = (N_NODES * HEADS + 255) / 256;
    const int NB  = (N_NODES + 255) / 256;
    const int MB  = (N_NODES + 127) / 128;  // 391

    // ---- layer 1: x[N,5] -> hbf[N,512] -> attn -> ghi/glo ----
    gemm5_kernel<<<(N_NODES * HC + 255) / 256, 256, 0, stream>>>(x, W1, hbf);
    score_kernel<8><<<NHB, 256, 0, stream>>>(hbf, as1, ad1, ssrc, sdst);
    softmax_kernel<8><<<NHB, 256, 0, stream>>>(rowptr, srcs, ssrc, sdst, pbuf, rden);
    agg8_kernel<<<N_NODES, 256, 0, stream>>>(hbf, pbuf, rowptr, srcs, rden, b1, ghi, glo);

    // ---- layer 2: g1 @ W2 (split-bf16 MFMA) -> hbf -> attn -> ghi/glo ----
    gemm_mfma<128, 2, 2><<<dim3(4, MB), 256, 0, stream>>>(ghi, glo, w2thi, w2tlo, hbf,
                                                          N_NODES, 512, 511);
    score_kernel<8><<<NHB, 256, 0, stream>>>(hbf, as2, ad2, ssrc, sdst);
    softmax_kernel<8><<<NHB, 256, 0, stream>>>(rowptr, srcs, ssrc, sdst, pbuf, rden);
    agg8_kernel<<<N_NODES, 256, 0, stream>>>(hbf, pbuf, rowptr, srcs, rden, b2, ghi, glo);

    // ---- layer 3: g2 @ W3 (split-bf16 MFMA) -> hbf[N,64] -> attn (1 head) -> g3 ----
    gemm_mfma<64, 2, 1><<<dim3(1, MB), 128, 0, stream>>>(ghi, glo, w3thi, w3tlo, hbf,
                                                         N_NODES, 64, 63);
    score_kernel<1><<<NB, 256, 0, stream>>>(hbf, as3, ad3, ssrc, sdst);
    softmax_kernel<1><<<NB, 256, 0, stream>>>(rowptr, srcs, ssrc, sdst, pbuf, rden);
    agg1_kernel<<<N_NODES, 64, 0, stream>>>(hbf, pbuf, rowptr, srcs, rden, b3, g3);

    // ---- classifier ----
    cls_kernel<<<NB, 256, 0, stream>>>(g3, Wc, bc, (float*)d_out);
}

// Round 5
// 606.559 us; speedup vs baseline: 1.9375x; 1.1331x over previous
//
#include <hip/hip_runtime.h>
#include <hip/hip_bf16.h>
#include <math.h>

#define N_NODES 50000
#define N_EDGES 400000
#define E_TOT   (N_EDGES + N_NODES)   // self loops appended
#define HEADS   8
#define HID     64
#define HC      (HEADS * HID)         // 512
#define NBLK    ((N_NODES + 255) / 256)  // 196 scan blocks

typedef __attribute__((ext_vector_type(8))) short bf16x8;  // 8 bf16 (4 VGPRs)
typedef __attribute__((ext_vector_type(4))) float f32x4;

__device__ __forceinline__ float elu1(float x) { return x > 0.f ? x : __expf(x) - 1.f; }

// round-to-nearest-even fp32 -> bf16 (raw ushort)
__device__ __forceinline__ unsigned short f2bf(float x) {
    unsigned u = __float_as_uint(x);
    unsigned r = (u + 0x7FFFu + ((u >> 16) & 1u)) >> 16;
    return (unsigned short)r;
}
__device__ __forceinline__ float bf2f(unsigned short h) {
    return __uint_as_float(((unsigned)h) << 16);
}

// ---------------- CSR build (by dst) ----------------
__global__ void hist_kernel(const int* __restrict__ dst, int* __restrict__ deg) {
    int e = blockIdx.x * blockDim.x + threadIdx.x;
    if (e >= E_TOT) return;
    int d = (e < N_EDGES) ? dst[e] : (e - N_EDGES);
    atomicAdd(&deg[d], 1);
}

// 1) per-block sums of deg
__global__ __launch_bounds__(256) void deg_partial_kernel(const int* __restrict__ deg,
                                                          int* __restrict__ psum) {
    __shared__ int sm[256];
    int t = threadIdx.x;
    int idx = blockIdx.x * 256 + t;
    int v = (idx < N_NODES) ? deg[idx] : 0;
    sm[t] = v;
    __syncthreads();
    for (int off = 128; off >= 1; off >>= 1) {
        if (t < off) sm[t] += sm[t + off];
        __syncthreads();
    }
    if (t == 0) psum[blockIdx.x] = sm[0];
}

// 2) exclusive scan of the NBLK block sums (single block)
__global__ __launch_bounds__(256) void scan_partial_kernel(int* __restrict__ psum) {
    __shared__ int sm[256];
    int t = threadIdx.x;
    int v = (t < NBLK) ? psum[t] : 0;
    sm[t] = v;
    __syncthreads();
    for (int off = 1; off < 256; off <<= 1) {
        int add = (t >= off) ? sm[t - off] : 0;
        __syncthreads();
        sm[t] += add;
        __syncthreads();
    }
    if (t < NBLK) psum[t] = sm[t] - v;  // exclusive
}

// 3) per-chunk exclusive scan + block offset -> rowptr, cursor
__global__ __launch_bounds__(256) void rowptr_kernel(const int* __restrict__ deg,
                                                     const int* __restrict__ psum,
                                                     int* __restrict__ rowptr,
                                                     int* __restrict__ cursor) {
    __shared__ int sm[256];
    int t = threadIdx.x;
    int idx = blockIdx.x * 256 + t;
    int v = (idx < N_NODES) ? deg[idx] : 0;
    sm[t] = v;
    __syncthreads();
    for (int off = 1; off < 256; off <<= 1) {
        int add = (t >= off) ? sm[t - off] : 0;
        __syncthreads();
        sm[t] += add;
        __syncthreads();
    }
    if (idx < N_NODES) {
        int r = psum[blockIdx.x] + sm[t] - v;  // exclusive
        rowptr[idx] = r;
        cursor[idx] = r;
    }
    if (idx == 0) rowptr[N_NODES] = E_TOT;
}

__global__ void scatter_kernel(const int* __restrict__ srcrow, const int* __restrict__ dstrow,
                               int* __restrict__ cursor, int* __restrict__ src_sorted) {
    int e = blockIdx.x * blockDim.x + threadIdx.x;
    if (e >= E_TOT) return;
    int s, d;
    if (e < N_EDGES) { s = srcrow[e]; d = dstrow[e]; }
    else             { s = d = e - N_EDGES; }
    int pos = atomicAdd(&cursor[d], 1);
    src_sorted[pos] = s;
}

// ---------------- Layer 1 GEMM: [N,5] @ [5,512] -> bf16 h ----------------
__global__ void gemm5_kernel(const float* __restrict__ x, const float* __restrict__ W,
                             unsigned short* __restrict__ h) {
    int gid = blockIdx.x * blockDim.x + threadIdx.x;
    if (gid >= N_NODES * HC) return;
    int n = gid >> 9, c = gid & 511;
    const float* xr = x + n * 5;
    float acc = xr[0] * W[c] + xr[1] * W[512 + c] + xr[2] * W[1024 + c] +
                xr[3] * W[1536 + c] + xr[4] * W[2048 + c];
    h[gid] = f2bf(acc);
}

// ---------------- W -> W^T split (hi/lo bf16): W[512][NCOL] -> Wt[NCOL][512] ----------------
template <int NCOL>
__global__ void wsplit_kernel(const float* __restrict__ W, unsigned short* __restrict__ hi,
                              unsigned short* __restrict__ lo) {
    int idx = blockIdx.x * 256 + threadIdx.x;
    if (idx >= 512 * NCOL) return;
    int k = idx / NCOL, n = idx % NCOL;
    float v = W[idx];
    unsigned short h = f2bf(v);
    unsigned short l = f2bf(v - bf2f(h));
    hi[(size_t)n * 512 + k] = h;
    lo[(size_t)n * 512 + k] = l;
}

// ---------------- split-bf16 MFMA GEMM ----------------
// A (hi/lo): [M][512] bf16 row-major. B (hi/lo): [Ncols][512] bf16 (W^T). C: [M][Nout] bf16.
// LDS tile: per row 64B (32 bf16 of K-window); 16B-slot p holds k-chunk g = p ^ ((row>>1)&3)
// (XOR swizzle via pre-swizzled global source + matching swizzled ds_read; rule #21).
template <int ROWS, int NW>
__device__ __forceinline__ void stage_tile(const unsigned short* __restrict__ src, int row0,
                                           int maxRow, int k0, char* lds, int wave, int lane) {
    constexpr int CHUNKS = ROWS / 16;  // 1KB chunks (16 rows x 64B)
    for (int c = wave; c < CHUNKS; c += NW) {
        int r = c * 16 + (lane >> 2);
        int p = lane & 3;
        int g = p ^ ((r >> 1) & 3);
        int gr = row0 + r;
        if (gr > maxRow) gr = maxRow;  // tail clamp; result write-guarded
        const unsigned short* gp = src + (size_t)gr * 512 + k0 + g * 8;
        __builtin_amdgcn_global_load_lds((const __attribute__((address_space(1))) void*)gp,
                                         (__attribute__((address_space(3))) void*)(lds + c * 1024),
                                         16, 0, 0);
    }
}

template <int BN, int WM, int WN>
__global__ __launch_bounds__(WM * WN * 64) void gemm_mfma(
    const unsigned short* __restrict__ Ahi, const unsigned short* __restrict__ Alo,
    const unsigned short* __restrict__ Bhi, const unsigned short* __restrict__ Blo,
    unsigned short* __restrict__ C, int M, int Nout, int maxRowB) {
    constexpr int BM = 128;
    constexpr int NW = WM * WN;
    __shared__ __attribute__((aligned(16))) char ldsAhi[BM * 64];
    __shared__ __attribute__((aligned(16))) char ldsAlo[BM * 64];
    __shared__ __attribute__((aligned(16))) char ldsBhi[BN * 64];
    __shared__ __attribute__((aligned(16))) char ldsBlo[BN * 64];
    const int t = threadIdx.x, lane = t & 63, wave = t >> 6;
    const int wr = wave / WN, wc = wave % WN;
    const int m0 = blockIdx.y * BM, n0 = blockIdx.x * BN;

    int offA[4], offB[4];
#pragma unroll
    for (int s = 0; s < 4; ++s) {
        int rA = wr * 64 + s * 16 + (lane & 15);
        offA[s] = rA * 64 + ((((lane >> 4) ^ ((rA >> 1) & 3))) << 4);
        int rB = wc * 64 + s * 16 + (lane & 15);
        offB[s] = rB * 64 + ((((lane >> 4) ^ ((rB >> 1) & 3))) << 4);
    }

    f32x4 acc[4][4] = {};

    for (int k0 = 0; k0 < 512; k0 += 32) {
        stage_tile<BM, NW>(Ahi, m0, M - 1, k0, ldsAhi, wave, lane);
        stage_tile<BM, NW>(Alo, m0, M - 1, k0, ldsAlo, wave, lane);
        stage_tile<BN, NW>(Bhi, n0, maxRowB, k0, ldsBhi, wave, lane);
        stage_tile<BN, NW>(Blo, n0, maxRowB, k0, ldsBlo, wave, lane);
        __syncthreads();

        bf16x8 ah[4], al[4], bh[4], bl[4];
#pragma unroll
        for (int s = 0; s < 4; ++s) {
            ah[s] = *(const bf16x8*)(ldsAhi + offA[s]);
            al[s] = *(const bf16x8*)(ldsAlo + offA[s]);
            bh[s] = *(const bf16x8*)(ldsBhi + offB[s]);
            bl[s] = *(const bf16x8*)(ldsBlo + offB[s]);
        }
#pragma unroll
        for (int i = 0; i < 4; ++i)
#pragma unroll
            for (int j = 0; j < 4; ++j) {
                acc[i][j] = __builtin_amdgcn_mfma_f32_16x16x32_bf16(ah[i], bh[j], acc[i][j], 0, 0, 0);
                acc[i][j] = __builtin_amdgcn_mfma_f32_16x16x32_bf16(ah[i], bl[j], acc[i][j], 0, 0, 0);
                acc[i][j] = __builtin_amdgcn_mfma_f32_16x16x32_bf16(al[i], bh[j], acc[i][j], 0, 0, 0);
            }
        __syncthreads();
    }

    // C/D layout (m89-verified): col = lane&15, row = (lane>>4)*4 + reg
#pragma unroll
    for (int i = 0; i < 4; ++i) {
        int row = m0 + wr * 64 + i * 16 + ((lane >> 4) << 2);
#pragma unroll
        for (int j = 0; j < 4; ++j) {
            int col = n0 + wc * 64 + j * 16 + (lane & 15);
            f32x4 v = acc[i][j];
#pragma unroll
            for (int r = 0; r < 4; ++r) {
                if (row + r < M) C[(size_t)(row + r) * Nout + col] = f2bf(v[r]);
            }
        }
    }
}

// ---------------- attention scores from bf16 h: s_src/s_dst [N,H] ----------------
template <int H>
__global__ void score_kernel(const unsigned short* __restrict__ h,
                             const float* __restrict__ a_src, const float* __restrict__ a_dst,
                             float* __restrict__ ssrc, float* __restrict__ sdst) {
    int gid = blockIdx.x * blockDim.x + threadIdx.x;
    if (gid >= N_NODES * H) return;
    int n = gid / H, hh = gid % H;
    const unsigned short* hp = h + (size_t)n * (H * 64) + hh * 64;
    const float* asp = a_src + hh * 64;
    const float* adp = a_dst + hh * 64;
    float s1 = 0.f, s2 = 0.f;
#pragma unroll
    for (int k = 0; k < 64; k += 8) {
        uint4 hv = *(const uint4*)(hp + k);
        const unsigned u[4] = {hv.x, hv.y, hv.z, hv.w};
#pragma unroll
        for (int q = 0; q < 4; ++q) {
            float f0 = bf2f((unsigned short)(u[q] & 0xffff));
            float f1 = bf2f((unsigned short)(u[q] >> 16));
            s1 = fmaf(f0, asp[k + 2 * q], fmaf(f1, asp[k + 2 * q + 1], s1));
            s2 = fmaf(f0, adp[k + 2 * q], fmaf(f1, adp[k + 2 * q + 1], s2));
        }
    }
    ssrc[gid] = s1;
    sdst[gid] = s2;
}

// ---------------- per-(dst,head) softmax ----------------
// pass 1: gather scores (4-wide pipelined), leaky-relu, store e to p, track max
// pass 2: sequential re-read of p (L1-resident), exp, store back, sum
template <int H>
__global__ void softmax_kernel(const int* __restrict__ rowptr, const int* __restrict__ srcs,
                               const float* __restrict__ ssrc, const float* __restrict__ sdst,
                               float* __restrict__ p, float* __restrict__ rden) {
    int gid = blockIdx.x * blockDim.x + threadIdx.x;
    if (gid >= N_NODES * H) return;
    int n = gid / H, hh = gid % H;
    int lo = rowptr[n], hi = rowptr[n + 1];
    float sd = sdst[gid];
    float m0 = -3.4e38f, m1 = -3.4e38f, m2 = -3.4e38f, m3 = -3.4e38f;
    int j = lo;
    for (; j + 4 <= hi; j += 4) {
        int s0 = srcs[j], s1 = srcs[j + 1], s2 = srcs[j + 2], s3 = srcs[j + 3];
        float v0 = ssrc[s0 * H + hh] + sd;
        float v1 = ssrc[s1 * H + hh] + sd;
        float v2 = ssrc[s2 * H + hh] + sd;
        float v3 = ssrc[s3 * H + hh] + sd;
        v0 = v0 > 0.f ? v0 : 0.2f * v0;
        v1 = v1 > 0.f ? v1 : 0.2f * v1;
        v2 = v2 > 0.f ? v2 : 0.2f * v2;
        v3 = v3 > 0.f ? v3 : 0.2f * v3;
        p[(size_t)j * H + hh] = v0;
        p[(size_t)(j + 1) * H + hh] = v1;
        p[(size_t)(j + 2) * H + hh] = v2;
        p[(size_t)(j + 3) * H + hh] = v3;
        m0 = fmaxf(m0, v0); m1 = fmaxf(m1, v1);
        m2 = fmaxf(m2, v2); m3 = fmaxf(m3, v3);
    }
    for (; j < hi; ++j) {
        float v = ssrc[srcs[j] * H + hh] + sd;
        v = v > 0.f ? v : 0.2f * v;
        p[(size_t)j * H + hh] = v;
        m0 = fmaxf(m0, v);
    }
    float mx = fmaxf(fmaxf(m0, m1), fmaxf(m2, m3));
    float sum = 0.f;
    for (j = lo; j < hi; ++j) {
        float pe = __expf(p[(size_t)j * H + hh] - mx);
        p[(size_t)j * H + hh] = pe;
        sum += pe;
    }
    rden[gid] = 1.f / (sum + 1e-16f);
}

// ---------------- gather-aggregate (8 heads, 512 ch, bf16 h) + bias + ELU + hi/lo split out ----
// 4-wide manual pipeline: 4 independent src/h/p loads in flight (latency-bound fix, R4).
__global__ __launch_bounds__(256) void agg8_kernel(const unsigned short* __restrict__ h,
                                                   const float* __restrict__ p,
                                                   const int* __restrict__ rowptr,
                                                   const int* __restrict__ srcs,
                                                   const float* __restrict__ rden,
                                                   const float* __restrict__ bias,
                                                   unsigned short* __restrict__ outHi,
                                                   unsigned short* __restrict__ outLo) {
    int n = blockIdx.x;
    int t = threadIdx.x;           // pair index: channels 2t, 2t+1 (same head)
    int hh = t >> 5;               // (2t)/64
    int lo = rowptr[n], hi = rowptr[n + 1];
    float rd = rden[n * 8 + hh];
    float a0 = 0.f, a1 = 0.f, b0 = 0.f, b1 = 0.f;
    float c0 = 0.f, c1 = 0.f, d0 = 0.f, d1 = 0.f;
    int j = lo;
    for (; j + 4 <= hi; j += 4) {
        int s0 = srcs[j], s1 = srcs[j + 1], s2 = srcs[j + 2], s3 = srcs[j + 3];
        unsigned v0 = *(const unsigned*)(h + (size_t)s0 * 512 + 2 * t);
        unsigned v1 = *(const unsigned*)(h + (size_t)s1 * 512 + 2 * t);
        unsigned v2 = *(const unsigned*)(h + (size_t)s2 * 512 + 2 * t);
        unsigned v3 = *(const unsigned*)(h + (size_t)s3 * 512 + 2 * t);
        float p0 = p[(size_t)j * 8 + hh];
        float p1 = p[(size_t)(j + 1) * 8 + hh];
        float p2 = p[(size_t)(j + 2) * 8 + hh];
        float p3 = p[(size_t)(j + 3) * 8 + hh];
        a0 = fmaf(p0, bf2f((unsigned short)(v0 & 0xffff)), a0);
        a1 = fmaf(p0, bf2f((unsigned short)(v0 >> 16)), a1);
        b0 = fmaf(p1, bf2f((unsigned short)(v1 & 0xffff)), b0);
        b1 = fmaf(p1, bf2f((unsigned short)(v1 >> 16)), b1);
        c0 = fmaf(p2, bf2f((unsigned short)(v2 & 0xffff)), c0);
        c1 = fmaf(p2, bf2f((unsigned short)(v2 >> 16)), c1);
        d0 = fmaf(p3, bf2f((unsigned short)(v3 & 0xffff)), d0);
        d1 = fmaf(p3, bf2f((unsigned short)(v3 >> 16)), d1);
    }
    for (; j < hi; ++j) {
        int s = srcs[j];
        unsigned v = *(const unsigned*)(h + (size_t)s * 512 + 2 * t);
        float pj = p[(size_t)j * 8 + hh];
        a0 = fmaf(pj, bf2f((unsigned short)(v & 0xffff)), a0);
        a1 = fmaf(pj, bf2f((unsigned short)(v >> 16)), a1);
    }
    float s0 = (a0 + b0) + (c0 + d0);
    float s1 = (a1 + b1) + (c1 + d1);
    float2 bv = *(const float2*)(bias + 2 * t);
    float v0 = elu1(s0 * rd + bv.x);
    float v1 = elu1(s1 * rd + bv.y);
    unsigned short h0 = f2bf(v0), h1 = f2bf(v1);
    unsigned hiPack = (unsigned)h0 | ((unsigned)h1 << 16);
    unsigned loPack = (unsigned)f2bf(v0 - bf2f(h0)) | ((unsigned)f2bf(v1 - bf2f(h1)) << 16);
    *(unsigned*)(outHi + (size_t)n * 512 + 2 * t) = hiPack;
    *(unsigned*)(outLo + (size_t)n * 512 + 2 * t) = loPack;
}

// ---------------- gather-aggregate (1 head, 64 ch, bf16 h) + bias + ELU -> fp32 ----------------
__global__ __launch_bounds__(64) void agg1_kernel(const unsigned short* __restrict__ h,
                                                  const float* __restrict__ p,
                                                  const int* __restrict__ rowptr,
                                                  const int* __restrict__ srcs,
                                                  const float* __restrict__ rden,
                                                  const float* __restrict__ bias,
                                                  float* __restrict__ out) {
    int n = blockIdx.x;
    int t = threadIdx.x;
    int lo = rowptr[n], hi = rowptr[n + 1];
    float rd = rden[n];
    float a = 0.f, b = 0.f, c = 0.f, d = 0.f;
    int j = lo;
    for (; j + 4 <= hi; j += 4) {
        int s0 = srcs[j], s1 = srcs[j + 1], s2 = srcs[j + 2], s3 = srcs[j + 3];
        float h0 = bf2f(h[(size_t)s0 * 64 + t]);
        float h1 = bf2f(h[(size_t)s1 * 64 + t]);
        float h2 = bf2f(h[(size_t)s2 * 64 + t]);
        float h3 = bf2f(h[(size_t)s3 * 64 + t]);
        a = fmaf(p[j], h0, a);
        b = fmaf(p[j + 1], h1, b);
        c = fmaf(p[j + 2], h2, c);
        d = fmaf(p[j + 3], h3, d);
    }
    for (; j < hi; ++j) {
        a = fmaf(p[j], bf2f(h[(size_t)srcs[j] * 64 + t]), a);
    }
    float acc = (a + b) + (c + d);
    out[(size_t)n * 64 + t] = elu1(acc * rd + bias[t]);
}

// ---------------- classifier: sigmoid(h3 @ Wc + bc) ----------------
__global__ void cls_kernel(const float* __restrict__ h, const float* __restrict__ Wc,
                           const float* __restrict__ bc, float* __restrict__ out) {
    int n = blockIdx.x * blockDim.x + threadIdx.x;
    if (n >= N_NODES) return;
    const float* hp = h + (size_t)n * 64;
    float s = bc[0];
#pragma unroll
    for (int k = 0; k < 64; k += 4) {
        float4 hv = *(const float4*)(hp + k);
        float4 wv = *(const float4*)(Wc + k);
        s += hv.x * wv.x + hv.y * wv.y + hv.z * wv.z + hv.w * wv.w;
    }
    out[n] = 1.f / (1.f + __expf(-s));
}

extern "C" void kernel_launch(void* const* d_in, const int* in_sizes, int n_in,
                              void* d_out, int out_size, void* d_ws, size_t ws_size,
                              hipStream_t stream) {
    const float* x   = (const float*)d_in[0];
    const int*   ei  = (const int*)d_in[1];
    const int* src_row = ei;
    const int* dst_row = ei + N_EDGES;
    const float* W1  = (const float*)d_in[2];
    const float* as1 = (const float*)d_in[3];
    const float* ad1 = (const float*)d_in[4];
    const float* b1  = (const float*)d_in[5];
    const float* W2  = (const float*)d_in[6];
    const float* as2 = (const float*)d_in[7];
    const float* ad2 = (const float*)d_in[8];
    const float* b2  = (const float*)d_in[9];
    const float* W3  = (const float*)d_in[10];
    const float* as3 = (const float*)d_in[11];
    const float* ad3 = (const float*)d_in[12];
    const float* b3  = (const float*)d_in[13];
    const float* Wc  = (const float*)d_in[14];
    const float* bc  = (const float*)d_in[15];

    char* w = (char*)d_ws;
    auto alloc = [&](size_t bytes) -> void* {
        void* ptr = (void*)w;
        w += (bytes + 255) & ~(size_t)255;
        return ptr;
    };
    int*   deg    = (int*)alloc((size_t)N_NODES * 4);
    int*   rowptr = (int*)alloc((size_t)(N_NODES + 1) * 4);
    int*   cursor = (int*)alloc((size_t)N_NODES * 4);
    int*   srcs   = (int*)alloc((size_t)E_TOT * 4);
    int*   psum   = (int*)alloc((size_t)NBLK * 4);
    float* pbuf   = (float*)alloc((size_t)E_TOT * HEADS * 4);
    float* ssrc   = (float*)alloc((size_t)N_NODES * HEADS * 4);
    float* sdst   = (float*)alloc((size_t)N_NODES * HEADS * 4);
    float* rden   = (float*)alloc((size_t)N_NODES * HEADS * 4);
    unsigned short* hbf = (unsigned short*)alloc((size_t)N_NODES * HC * 2);  // bf16 h (GEMM out)
    unsigned short* ghi = (unsigned short*)alloc((size_t)N_NODES * HC * 2);  // agg out hi
    unsigned short* glo = (unsigned short*)alloc((size_t)N_NODES * HC * 2);  // agg out lo
    unsigned short* w2thi = (unsigned short*)alloc((size_t)512 * 512 * 2);
    unsigned short* w2tlo = (unsigned short*)alloc((size_t)512 * 512 * 2);
    unsigned short* w3thi = (unsigned short*)alloc((size_t)64 * 512 * 2);
    unsigned short* w3tlo = (unsigned short*)alloc((size_t)64 * 512 * 2);
    float* g3 = (float*)ghi;  // layer-3 agg out (fp32, 12.8MB) aliases ghi (free by then)

    hipMemsetAsync(deg, 0, (size_t)N_NODES * 4, stream);

    const int EB = (E_TOT + 255) / 256;
    hist_kernel<<<EB, 256, 0, stream>>>(dst_row, deg);
    deg_partial_kernel<<<NBLK, 256, 0, stream>>>(deg, psum);
    scan_partial_kernel<<<1, 256, 0, stream>>>(psum);
    rowptr_kernel<<<NBLK, 256, 0, stream>>>(deg, psum, rowptr, cursor);
    scatter_kernel<<<EB, 256, 0, stream>>>(src_row, dst_row, cursor, srcs);

    // weight transpose+split (tiny; once per call)
    wsplit_kernel<512><<<(512 * 512 + 255) / 256, 256, 0, stream>>>(W2, w2thi, w2tlo);
    wsplit_kernel<64><<<(512 * 64 + 255) / 256, 256, 0, stream>>>(W3, w3thi, w3tlo);

    const int NHB = (N_NODES * HEADS + 255) / 256;
    const int NB  = (N_NODES + 255) / 256;
    const int MB  = (N_NODES + 127) / 128;  // 391

    // ---- layer 1: x[N,5] -> hbf[N,512] -> attn -> ghi/glo ----
    gemm5_kernel<<<(N_NODES * HC + 255) / 256, 256, 0, stream>>>(x, W1, hbf);
    score_kernel<8><<<NHB, 256, 0, stream>>>(hbf, as1, ad1, ssrc, sdst);
    softmax_kernel<8><<<NHB, 256, 0, stream>>>(rowptr, srcs, ssrc, sdst, pbuf, rden);
    agg8_kernel<<<N_NODES, 256, 0, stream>>>(hbf, pbuf, rowptr, srcs, rden, b1, ghi, glo);

    // ---- layer 2: g1 @ W2 (split-bf16 MFMA) -> hbf -> attn -> ghi/glo ----
    gemm_mfma<128, 2, 2><<<dim3(4, MB), 256, 0, stream>>>(ghi, glo, w2thi, w2tlo, hbf,
                                                          N_NODES, 512, 511);
    score_kernel<8><<<NHB, 256, 0, stream>>>(hbf, as2, ad2, ssrc, sdst);
    softmax_kernel<8><<<NHB, 256, 0, stream>>>(rowptr, srcs, ssrc, sdst, pbuf, rden);
    agg8_kernel<<<N_NODES, 256, 0, stream>>>(hbf, pbuf, rowptr, srcs, rden, b2, ghi, glo);

    // ---- layer 3: g2 @ W3 (split-bf16 MFMA) -> hbf[N,64] -> attn (1 head) -> g3 ----
    gemm_mfma<64, 2, 1><<<dim3(1, MB), 128, 0, stream>>>(ghi, glo, w3thi, w3tlo, hbf,
                                                         N_NODES, 64, 63);
    score_kernel<1><<<NB, 256, 0, stream>>>(hbf, as3, ad3, ssrc, sdst);
    softmax_kernel<1><<<NB, 256, 0, stream>>>(rowptr, srcs, ssrc, sdst, pbuf, rden);
    agg1_kernel<<<N_NODES, 64, 0, stream>>>(hbf, pbuf, rowptr, srcs, rden, b3, g3);

    // ---- classifier ----
    cls_kernel<<<NB, 256, 0, stream>>>(g3, Wc, bc, (float*)d_out);
}

// Round 6
// 595.024 us; speedup vs baseline: 1.9750x; 1.0194x over previous
//
#include <hip/hip_runtime.h>
#include <hip/hip_bf16.h>
#include <math.h>

#define N_NODES 50000
#define N_EDGES 400000
#define E_TOT   (N_EDGES + N_NODES)   // self loops appended
#define HEADS   8
#define HID     64
#define HC      (HEADS * HID)         // 512
#define NBLK    ((N_NODES + 255) / 256)  // 196 scan blocks

typedef __attribute__((ext_vector_type(8))) short bf16x8;  // 8 bf16 (4 VGPRs)
typedef __attribute__((ext_vector_type(4))) float f32x4;

__device__ __forceinline__ float elu1(float x) { return x > 0.f ? x : __expf(x) - 1.f; }

// round-to-nearest-even fp32 -> bf16 (raw ushort)
__device__ __forceinline__ unsigned short f2bf(float x) {
    unsigned u = __float_as_uint(x);
    unsigned r = (u + 0x7FFFu + ((u >> 16) & 1u)) >> 16;
    return (unsigned short)r;
}
__device__ __forceinline__ float bf2f(unsigned short h) {
    return __uint_as_float(((unsigned)h) << 16);
}

// ---------------- CSR build (by dst) ----------------
__global__ void hist_kernel(const int* __restrict__ dst, int* __restrict__ deg) {
    int e = blockIdx.x * blockDim.x + threadIdx.x;
    if (e >= E_TOT) return;
    int d = (e < N_EDGES) ? dst[e] : (e - N_EDGES);
    atomicAdd(&deg[d], 1);
}

__global__ __launch_bounds__(256) void deg_partial_kernel(const int* __restrict__ deg,
                                                          int* __restrict__ psum) {
    __shared__ int sm[256];
    int t = threadIdx.x;
    int idx = blockIdx.x * 256 + t;
    int v = (idx < N_NODES) ? deg[idx] : 0;
    sm[t] = v;
    __syncthreads();
    for (int off = 128; off >= 1; off >>= 1) {
        if (t < off) sm[t] += sm[t + off];
        __syncthreads();
    }
    if (t == 0) psum[blockIdx.x] = sm[0];
}

__global__ __launch_bounds__(256) void scan_partial_kernel(int* __restrict__ psum) {
    __shared__ int sm[256];
    int t = threadIdx.x;
    int v = (t < NBLK) ? psum[t] : 0;
    sm[t] = v;
    __syncthreads();
    for (int off = 1; off < 256; off <<= 1) {
        int add = (t >= off) ? sm[t - off] : 0;
        __syncthreads();
        sm[t] += add;
        __syncthreads();
    }
    if (t < NBLK) psum[t] = sm[t] - v;  // exclusive
}

__global__ __launch_bounds__(256) void rowptr_kernel(const int* __restrict__ deg,
                                                     const int* __restrict__ psum,
                                                     int* __restrict__ rowptr,
                                                     int* __restrict__ cursor) {
    __shared__ int sm[256];
    int t = threadIdx.x;
    int idx = blockIdx.x * 256 + t;
    int v = (idx < N_NODES) ? deg[idx] : 0;
    sm[t] = v;
    __syncthreads();
    for (int off = 1; off < 256; off <<= 1) {
        int add = (t >= off) ? sm[t - off] : 0;
        __syncthreads();
        sm[t] += add;
        __syncthreads();
    }
    if (idx < N_NODES) {
        int r = psum[blockIdx.x] + sm[t] - v;  // exclusive
        rowptr[idx] = r;
        cursor[idx] = r;
    }
    if (idx == 0) rowptr[N_NODES] = E_TOT;
}

__global__ void scatter_kernel(const int* __restrict__ srcrow, const int* __restrict__ dstrow,
                               int* __restrict__ cursor, int* __restrict__ src_sorted) {
    int e = blockIdx.x * blockDim.x + threadIdx.x;
    if (e >= E_TOT) return;
    int s, d;
    if (e < N_EDGES) { s = srcrow[e]; d = dstrow[e]; }
    else             { s = d = e - N_EDGES; }
    int pos = atomicAdd(&cursor[d], 1);
    src_sorted[pos] = s;
}

// ---------------- Layer 1 GEMM: [N,5] @ [5,512] -> bf16 h ----------------
__global__ void gemm5_kernel(const float* __restrict__ x, const float* __restrict__ W,
                             unsigned short* __restrict__ h) {
    int gid = blockIdx.x * blockDim.x + threadIdx.x;
    if (gid >= N_NODES * HC) return;
    int n = gid >> 9, c = gid & 511;
    const float* xr = x + n * 5;
    float acc = xr[0] * W[c] + xr[1] * W[512 + c] + xr[2] * W[1024 + c] +
                xr[3] * W[1536 + c] + xr[4] * W[2048 + c];
    h[gid] = f2bf(acc);
}

// ---------------- W -> W^T split (hi/lo bf16): W[512][NCOL] -> Wt[NCOL][512] ----------------
template <int NCOL>
__global__ void wsplit_kernel(const float* __restrict__ W, unsigned short* __restrict__ hi,
                              unsigned short* __restrict__ lo) {
    int idx = blockIdx.x * 256 + threadIdx.x;
    if (idx >= 512 * NCOL) return;
    int k = idx / NCOL, n = idx % NCOL;
    float v = W[idx];
    unsigned short h = f2bf(v);
    unsigned short l = f2bf(v - bf2f(h));
    hi[(size_t)n * 512 + k] = h;
    lo[(size_t)n * 512 + k] = l;
}

// ---------------- split-bf16 MFMA GEMM, BK=64 full-line staging ----------------
// LDS per half-buffer: rows of 64B (32 bf16); 16B-slot p holds k-chunk g = p ^ ((row>>1)&3)
// (zero-bank-conflict layout, measured R5). For each row the two 16B half-line chunks
// [k0,k0+32) and [k0+32,k0+64) are issued back-to-back by the same wave -> both halves of
// every 128B cache line are consumed while in flight -> no half-line over-fetch (R5: 2.2x).
template <int ROWS, int NW>
__device__ __forceinline__ void stage_pair(const unsigned short* __restrict__ src, int row0,
                                           int maxRow, int k0, char* lds0, char* lds1,
                                           int wave, int lane) {
    constexpr int CHUNKS = ROWS / 16;  // 1KB chunks (16 rows x 64B) per half
    for (int c = wave; c < CHUNKS; c += NW) {
        int r = c * 16 + (lane >> 2);
        int p = lane & 3;
        int g = p ^ ((r >> 1) & 3);
        int gr = row0 + r;
        if (gr > maxRow) gr = maxRow;  // tail clamp; result write-guarded
        const unsigned short* gp = src + (size_t)gr * 512 + k0 + g * 8;
        __builtin_amdgcn_global_load_lds((const __attribute__((address_space(1))) void*)gp,
                                         (__attribute__((address_space(3))) void*)(lds0 + c * 1024),
                                         16, 0, 0);
        __builtin_amdgcn_global_load_lds((const __attribute__((address_space(1))) void*)(gp + 32),
                                         (__attribute__((address_space(3))) void*)(lds1 + c * 1024),
                                         16, 0, 0);
    }
}

template <int BM, int BN, int WM, int WN>
__global__ __launch_bounds__(WM * WN * 64) void gemm_mfma(
    const unsigned short* __restrict__ Ahi, const unsigned short* __restrict__ Alo,
    const unsigned short* __restrict__ Bhi, const unsigned short* __restrict__ Blo,
    unsigned short* __restrict__ C, int M, int Nout, int maxRowB) {
    constexpr int NW = WM * WN;
    constexpr int MI = BM / (16 * WM);
    constexpr int NI = BN / (16 * WN);
    constexpr int ABYTES = BM * 64;
    constexpr int BBYTES = BN * 64;
    __shared__ __attribute__((aligned(16))) char lds[(ABYTES + BBYTES) * 4];
    char* const pAhi0 = lds;
    char* const pAhi1 = pAhi0 + ABYTES;
    char* const pAlo0 = pAhi1 + ABYTES;
    char* const pAlo1 = pAlo0 + ABYTES;
    char* const pBhi0 = pAlo1 + ABYTES;
    char* const pBhi1 = pBhi0 + BBYTES;
    char* const pBlo0 = pBhi1 + BBYTES;
    char* const pBlo1 = pBlo0 + BBYTES;

    const int t = threadIdx.x, lane = t & 63, wave = t >> 6;
    const int wr = wave / WN, wc = wave % WN;
    const int m0 = blockIdx.y * BM, n0 = blockIdx.x * BN;

    int offA[MI], offB[NI];
#pragma unroll
    for (int s = 0; s < MI; ++s) {
        int rA = (wr * MI + s) * 16 + (lane & 15);
        offA[s] = rA * 64 + ((((lane >> 4) ^ ((rA >> 1) & 3))) << 4);
    }
#pragma unroll
    for (int s = 0; s < NI; ++s) {
        int rB = (wc * NI + s) * 16 + (lane & 15);
        offB[s] = rB * 64 + ((((lane >> 4) ^ ((rB >> 1) & 3))) << 4);
    }

    f32x4 acc[MI][NI] = {};

    for (int k0 = 0; k0 < 512; k0 += 64) {
        stage_pair<BM, NW>(Ahi, m0, M - 1, k0, pAhi0, pAhi1, wave, lane);
        stage_pair<BM, NW>(Alo, m0, M - 1, k0, pAlo0, pAlo1, wave, lane);
        stage_pair<BN, NW>(Bhi, n0, maxRowB, k0, pBhi0, pBhi1, wave, lane);
        stage_pair<BN, NW>(Blo, n0, maxRowB, k0, pBlo0, pBlo1, wave, lane);
        __syncthreads();  // compiler drains vmcnt before barrier -> LDS valid

#pragma unroll
        for (int half = 0; half < 2; ++half) {
            const char* cAhi = half ? pAhi1 : pAhi0;
            const char* cAlo = half ? pAlo1 : pAlo0;
            const char* cBhi = half ? pBhi1 : pBhi0;
            const char* cBlo = half ? pBlo1 : pBlo0;
            bf16x8 ah[MI], al[MI], bh[NI], bl[NI];
#pragma unroll
            for (int s = 0; s < MI; ++s) {
                ah[s] = *(const bf16x8*)(cAhi + offA[s]);
                al[s] = *(const bf16x8*)(cAlo + offA[s]);
            }
#pragma unroll
            for (int s = 0; s < NI; ++s) {
                bh[s] = *(const bf16x8*)(cBhi + offB[s]);
                bl[s] = *(const bf16x8*)(cBlo + offB[s]);
            }
#pragma unroll
            for (int i = 0; i < MI; ++i)
#pragma unroll
                for (int j = 0; j < NI; ++j) {
                    acc[i][j] = __builtin_amdgcn_mfma_f32_16x16x32_bf16(ah[i], bh[j], acc[i][j], 0, 0, 0);
                    acc[i][j] = __builtin_amdgcn_mfma_f32_16x16x32_bf16(ah[i], bl[j], acc[i][j], 0, 0, 0);
                    acc[i][j] = __builtin_amdgcn_mfma_f32_16x16x32_bf16(al[i], bh[j], acc[i][j], 0, 0, 0);
                }
        }
        __syncthreads();
    }

    // C/D layout (m89-verified): col = lane&15, row = (lane>>4)*4 + reg
#pragma unroll
    for (int i = 0; i < MI; ++i) {
        int row = m0 + (wr * MI + i) * 16 + ((lane >> 4) << 2);
#pragma unroll
        for (int j = 0; j < NI; ++j) {
            int col = n0 + (wc * NI + j) * 16 + (lane & 15);
            f32x4 v = acc[i][j];
#pragma unroll
            for (int r = 0; r < 4; ++r) {
                if (row + r < M) C[(size_t)(row + r) * Nout + col] = f2bf(v[r]);
            }
        }
    }
}

// ---------------- attention scores from bf16 h: s_src/s_dst [N,H] ----------------
template <int H>
__global__ void score_kernel(const unsigned short* __restrict__ h,
                             const float* __restrict__ a_src, const float* __restrict__ a_dst,
                             float* __restrict__ ssrc, float* __restrict__ sdst) {
    int gid = blockIdx.x * blockDim.x + threadIdx.x;
    if (gid >= N_NODES * H) return;
    int n = gid / H, hh = gid % H;
    const unsigned short* hp = h + (size_t)n * (H * 64) + hh * 64;
    const float* asp = a_src + hh * 64;
    const float* adp = a_dst + hh * 64;
    float s1 = 0.f, s2 = 0.f;
#pragma unroll
    for (int k = 0; k < 64; k += 8) {
        uint4 hv = *(const uint4*)(hp + k);
        const unsigned u[4] = {hv.x, hv.y, hv.z, hv.w};
#pragma unroll
        for (int q = 0; q < 4; ++q) {
            float f0 = bf2f((unsigned short)(u[q] & 0xffff));
            float f1 = bf2f((unsigned short)(u[q] >> 16));
            s1 = fmaf(f0, asp[k + 2 * q], fmaf(f1, asp[k + 2 * q + 1], s1));
            s2 = fmaf(f0, adp[k + 2 * q], fmaf(f1, adp[k + 2 * q + 1], s2));
        }
    }
    ssrc[gid] = s1;
    sdst[gid] = s2;
}

// ---------------- per-(dst,head) softmax ----------------
template <int H>
__global__ void softmax_kernel(const int* __restrict__ rowptr, const int* __restrict__ srcs,
                               const float* __restrict__ ssrc, const float* __restrict__ sdst,
                               float* __restrict__ p, float* __restrict__ rden) {
    int gid = blockIdx.x * blockDim.x + threadIdx.x;
    if (gid >= N_NODES * H) return;
    int n = gid / H, hh = gid % H;
    int lo = rowptr[n], hi = rowptr[n + 1];
    float sd = sdst[gid];
    float m0 = -3.4e38f, m1 = -3.4e38f, m2 = -3.4e38f, m3 = -3.4e38f;
    int j = lo;
    for (; j + 4 <= hi; j += 4) {
        int s0 = srcs[j], s1 = srcs[j + 1], s2 = srcs[j + 2], s3 = srcs[j + 3];
        float v0 = ssrc[s0 * H + hh] + sd;
        float v1 = ssrc[s1 * H + hh] + sd;
        float v2 = ssrc[s2 * H + hh] + sd;
        float v3 = ssrc[s3 * H + hh] + sd;
        v0 = v0 > 0.f ? v0 : 0.2f * v0;
        v1 = v1 > 0.f ? v1 : 0.2f * v1;
        v2 = v2 > 0.f ? v2 : 0.2f * v2;
        v3 = v3 > 0.f ? v3 : 0.2f * v3;
        p[(size_t)j * H + hh] = v0;
        p[(size_t)(j + 1) * H + hh] = v1;
        p[(size_t)(j + 2) * H + hh] = v2;
        p[(size_t)(j + 3) * H + hh] = v3;
        m0 = fmaxf(m0, v0); m1 = fmaxf(m1, v1);
        m2 = fmaxf(m2, v2); m3 = fmaxf(m3, v3);
    }
    for (; j < hi; ++j) {
        float v = ssrc[srcs[j] * H + hh] + sd;
        v = v > 0.f ? v : 0.2f * v;
        p[(size_t)j * H + hh] = v;
        m0 = fmaxf(m0, v);
    }
    float mx = fmaxf(fmaxf(m0, m1), fmaxf(m2, m3));
    float sum = 0.f;
    for (j = lo; j < hi; ++j) {
        float pe = __expf(p[(size_t)j * H + hh] - mx);
        p[(size_t)j * H + hh] = pe;
        sum += pe;
    }
    rden[gid] = 1.f / (sum + 1e-16f);
}

// ---------------- gather-aggregate (8 heads, 512 ch, bf16 h) + bias + ELU + hi/lo split out ----
__global__ __launch_bounds__(256) void agg8_kernel(const unsigned short* __restrict__ h,
                                                   const float* __restrict__ p,
                                                   const int* __restrict__ rowptr,
                                                   const int* __restrict__ srcs,
                                                   const float* __restrict__ rden,
                                                   const float* __restrict__ bias,
                                                   unsigned short* __restrict__ outHi,
                                                   unsigned short* __restrict__ outLo) {
    int n = blockIdx.x;
    int t = threadIdx.x;           // pair index: channels 2t, 2t+1 (same head)
    int hh = t >> 5;               // (2t)/64
    int lo = rowptr[n], hi = rowptr[n + 1];
    float rd = rden[n * 8 + hh];
    float a0 = 0.f, a1 = 0.f, b0 = 0.f, b1 = 0.f;
    float c0 = 0.f, c1 = 0.f, d0 = 0.f, d1 = 0.f;
    int j = lo;
    for (; j + 4 <= hi; j += 4) {
        int s0 = srcs[j], s1 = srcs[j + 1], s2 = srcs[j + 2], s3 = srcs[j + 3];
        unsigned v0 = *(const unsigned*)(h + (size_t)s0 * 512 + 2 * t);
        unsigned v1 = *(const unsigned*)(h + (size_t)s1 * 512 + 2 * t);
        unsigned v2 = *(const unsigned*)(h + (size_t)s2 * 512 + 2 * t);
        unsigned v3 = *(const unsigned*)(h + (size_t)s3 * 512 + 2 * t);
        float p0 = p[(size_t)j * 8 + hh];
        float p1 = p[(size_t)(j + 1) * 8 + hh];
        float p2 = p[(size_t)(j + 2) * 8 + hh];
        float p3 = p[(size_t)(j + 3) * 8 + hh];
        a0 = fmaf(p0, bf2f((unsigned short)(v0 & 0xffff)), a0);
        a1 = fmaf(p0, bf2f((unsigned short)(v0 >> 16)), a1);
        b0 = fmaf(p1, bf2f((unsigned short)(v1 & 0xffff)), b0);
        b1 = fmaf(p1, bf2f((unsigned short)(v1 >> 16)), b1);
        c0 = fmaf(p2, bf2f((unsigned short)(v2 & 0xffff)), c0);
        c1 = fmaf(p2, bf2f((unsigned short)(v2 >> 16)), c1);
        d0 = fmaf(p3, bf2f((unsigned short)(v3 & 0xffff)), d0);
        d1 = fmaf(p3, bf2f((unsigned short)(v3 >> 16)), d1);
    }
    for (; j < hi; ++j) {
        int s = srcs[j];
        unsigned v = *(const unsigned*)(h + (size_t)s * 512 + 2 * t);
        float pj = p[(size_t)j * 8 + hh];
        a0 = fmaf(pj, bf2f((unsigned short)(v & 0xffff)), a0);
        a1 = fmaf(pj, bf2f((unsigned short)(v >> 16)), a1);
    }
    float s0 = (a0 + b0) + (c0 + d0);
    float s1 = (a1 + b1) + (c1 + d1);
    float2 bv = *(const float2*)(bias + 2 * t);
    float v0 = elu1(s0 * rd + bv.x);
    float v1 = elu1(s1 * rd + bv.y);
    unsigned short h0 = f2bf(v0), h1 = f2bf(v1);
    unsigned hiPack = (unsigned)h0 | ((unsigned)h1 << 16);
    unsigned loPack = (unsigned)f2bf(v0 - bf2f(h0)) | ((unsigned)f2bf(v1 - bf2f(h1)) << 16);
    *(unsigned*)(outHi + (size_t)n * 512 + 2 * t) = hiPack;
    *(unsigned*)(outLo + (size_t)n * 512 + 2 * t) = loPack;
}

// ---------------- gather-aggregate (1 head, 64 ch, bf16 h) + bias + ELU -> fp32 ----------------
__global__ __launch_bounds__(64) void agg1_kernel(const unsigned short* __restrict__ h,
                                                  const float* __restrict__ p,
                                                  const int* __restrict__ rowptr,
                                                  const int* __restrict__ srcs,
                                                  const float* __restrict__ rden,
                                                  const float* __restrict__ bias,
                                                  float* __restrict__ out) {
    int n = blockIdx.x;
    int t = threadIdx.x;
    int lo = rowptr[n], hi = rowptr[n + 1];
    float rd = rden[n];
    float a = 0.f, b = 0.f, c = 0.f, d = 0.f;
    int j = lo;
    for (; j + 4 <= hi; j += 4) {
        int s0 = srcs[j], s1 = srcs[j + 1], s2 = srcs[j + 2], s3 = srcs[j + 3];
        float h0 = bf2f(h[(size_t)s0 * 64 + t]);
        float h1 = bf2f(h[(size_t)s1 * 64 + t]);
        float h2 = bf2f(h[(size_t)s2 * 64 + t]);
        float h3 = bf2f(h[(size_t)s3 * 64 + t]);
        a = fmaf(p[j], h0, a);
        b = fmaf(p[j + 1], h1, b);
        c = fmaf(p[j + 2], h2, c);
        d = fmaf(p[j + 3], h3, d);
    }
    for (; j < hi; ++j) {
        a = fmaf(p[j], bf2f(h[(size_t)srcs[j] * 64 + t]), a);
    }
    float acc = (a + b) + (c + d);
    out[(size_t)n * 64 + t] = elu1(acc * rd + bias[t]);
}

// ---------------- classifier: sigmoid(h3 @ Wc + bc) ----------------
__global__ void cls_kernel(const float* __restrict__ h, const float* __restrict__ Wc,
                           const float* __restrict__ bc, float* __restrict__ out) {
    int n = blockIdx.x * blockDim.x + threadIdx.x;
    if (n >= N_NODES) return;
    const float* hp = h + (size_t)n * 64;
    float s = bc[0];
#pragma unroll
    for (int k = 0; k < 64; k += 4) {
        float4 hv = *(const float4*)(hp + k);
        float4 wv = *(const float4*)(Wc + k);
        s += hv.x * wv.x + hv.y * wv.y + hv.z * wv.z + hv.w * wv.w;
    }
    out[n] = 1.f / (1.f + __expf(-s));
}

extern "C" void kernel_launch(void* const* d_in, const int* in_sizes, int n_in,
                              void* d_out, int out_size, void* d_ws, size_t ws_size,
                              hipStream_t stream) {
    const float* x   = (const float*)d_in[0];
    const int*   ei  = (const int*)d_in[1];
    const int* src_row = ei;
    const int* dst_row = ei + N_EDGES;
    const float* W1  = (const float*)d_in[2];
    const float* as1 = (const float*)d_in[3];
    const float* ad1 = (const float*)d_in[4];
    const float* b1  = (const float*)d_in[5];
    const float* W2  = (const float*)d_in[6];
    const float* as2 = (const float*)d_in[7];
    const float* ad2 = (const float*)d_in[8];
    const float* b2  = (const float*)d_in[9];
    const float* W3  = (const float*)d_in[10];
    const float* as3 = (const float*)d_in[11];
    const float* ad3 = (const float*)d_in[12];
    const float* b3  = (const float*)d_in[13];
    const float* Wc  = (const float*)d_in[14];
    const float* bc  = (const float*)d_in[15];

    char* w = (char*)d_ws;
    auto alloc = [&](size_t bytes) -> void* {
        void* ptr = (void*)w;
        w += (bytes + 255) & ~(size_t)255;
        return ptr;
    };
    int*   deg    = (int*)alloc((size_t)N_NODES * 4);
    int*   rowptr = (int*)alloc((size_t)(N_NODES + 1) * 4);
    int*   cursor = (int*)alloc((size_t)N_NODES * 4);
    int*   srcs   = (int*)alloc((size_t)E_TOT * 4);
    int*   psum   = (int*)alloc((size_t)NBLK * 4);
    float* pbuf   = (float*)alloc((size_t)E_TOT * HEADS * 4);
    float* ssrc   = (float*)alloc((size_t)N_NODES * HEADS * 4);
    float* sdst   = (float*)alloc((size_t)N_NODES * HEADS * 4);
    float* rden   = (float*)alloc((size_t)N_NODES * HEADS * 4);
    unsigned short* hbf = (unsigned short*)alloc((size_t)N_NODES * HC * 2);  // bf16 h (GEMM out)
    unsigned short* ghi = (unsigned short*)alloc((size_t)N_NODES * HC * 2);  // agg out hi
    unsigned short* glo = (unsigned short*)alloc((size_t)N_NODES * HC * 2);  // agg out lo
    unsigned short* w2thi = (unsigned short*)alloc((size_t)512 * 512 * 2);
    unsigned short* w2tlo = (unsigned short*)alloc((size_t)512 * 512 * 2);
    unsigned short* w3thi = (unsigned short*)alloc((size_t)64 * 512 * 2);
    unsigned short* w3tlo = (unsigned short*)alloc((size_t)64 * 512 * 2);
    float* g3 = (float*)ghi;  // layer-3 agg out (fp32, 12.8MB) aliases ghi (free by then)

    hipMemsetAsync(deg, 0, (size_t)N_NODES * 4, stream);

    const int EB = (E_TOT + 255) / 256;
    hist_kernel<<<EB, 256, 0, stream>>>(dst_row, deg);
    deg_partial_kernel<<<NBLK, 256, 0, stream>>>(deg, psum);
    scan_partial_kernel<<<1, 256, 0, stream>>>(psum);
    rowptr_kernel<<<NBLK, 256, 0, stream>>>(deg, psum, rowptr, cursor);
    scatter_kernel<<<EB, 256, 0, stream>>>(src_row, dst_row, cursor, srcs);

    // weight transpose+split (tiny; once per call)
    wsplit_kernel<512><<<(512 * 512 + 255) / 256, 256, 0, stream>>>(W2, w2thi, w2tlo);
    wsplit_kernel<64><<<(512 * 64 + 255) / 256, 256, 0, stream>>>(W3, w3thi, w3tlo);

    const int NHB = (N_NODES * HEADS + 255) / 256;
    const int NB  = (N_NODES + 255) / 256;
    const int MB128 = (N_NODES + 127) / 128;  // 391
    const int MB64  = (N_NODES + 63) / 64;    // 782

    // ---- layer 1: x[N,5] -> hbf[N,512] -> attn -> ghi/glo ----
    gemm5_kernel<<<(N_NODES * HC + 255) / 256, 256, 0, stream>>>(x, W1, hbf);
    score_kernel<8><<<NHB, 256, 0, stream>>>(hbf, as1, ad1, ssrc, sdst);
    softmax_kernel<8><<<NHB, 256, 0, stream>>>(rowptr, srcs, ssrc, sdst, pbuf, rden);
    agg8_kernel<<<N_NODES, 256, 0, stream>>>(hbf, pbuf, rowptr, srcs, rden, b1, ghi, glo);

    // ---- layer 2: g1 @ W2 (split-bf16 MFMA, BK=64) -> hbf -> attn -> ghi/glo ----
    gemm_mfma<128, 128, 2, 2><<<dim3(4, MB128), 256, 0, stream>>>(ghi, glo, w2thi, w2tlo, hbf,
                                                                  N_NODES, 512, 511);
    score_kernel<8><<<NHB, 256, 0, stream>>>(hbf, as2, ad2, ssrc, sdst);
    softmax_kernel<8><<<NHB, 256, 0, stream>>>(rowptr, srcs, ssrc, sdst, pbuf, rden);
    agg8_kernel<<<N_NODES, 256, 0, stream>>>(hbf, pbuf, rowptr, srcs, rden, b2, ghi, glo);

    // ---- layer 3: g2 @ W3 (split-bf16 MFMA, BM=64 for parallelism) -> hbf[N,64] -> attn -> g3 ----
    gemm_mfma<64, 64, 2, 1><<<dim3(1, MB64), 128, 0, stream>>>(ghi, glo, w3thi, w3tlo, hbf,
                                                               N_NODES, 64, 63);
    score_kernel<1><<<NB, 256, 0, stream>>>(hbf, as3, ad3, ssrc, sdst);
    softmax_kernel<1><<<NB, 256, 0, stream>>>(rowptr, srcs, ssrc, sdst, pbuf, rden);
    agg1_kernel<<<N_NODES, 64, 0, stream>>>(hbf, pbuf, rowptr, srcs, rden, b3, g3);

    // ---- classifier ----
    cls_kernel<<<NB, 256, 0, stream>>>(g3, Wc, bc, (float*)d_out);
}

// Round 7
// 545.346 us; speedup vs baseline: 2.1549x; 1.0911x over previous
//
#include <hip/hip_runtime.h>
#include <hip/hip_bf16.h>
#include <math.h>

#define N_NODES 50000
#define N_EDGES 400000
#define E_TOT   (N_EDGES + N_NODES)   // self loops appended
#define HEADS   8
#define HID     64
#define HC      (HEADS * HID)         // 512
#define NBLK    ((N_NODES + 255) / 256)  // 196 scan blocks

typedef __attribute__((ext_vector_type(8))) short bf16x8;  // 8 bf16 (4 VGPRs)
typedef __attribute__((ext_vector_type(4))) float f32x4;

__device__ __forceinline__ float elu1(float x) { return x > 0.f ? x : __expf(x) - 1.f; }

// round-to-nearest-even fp32 -> bf16 (raw ushort)
__device__ __forceinline__ unsigned short f2bf(float x) {
    unsigned u = __float_as_uint(x);
    unsigned r = (u + 0x7FFFu + ((u >> 16) & 1u)) >> 16;
    return (unsigned short)r;
}
__device__ __forceinline__ float bf2f(unsigned short h) {
    return __uint_as_float(((unsigned)h) << 16);
}

// ---------------- CSR build (by dst) ----------------
__global__ void hist_kernel(const int* __restrict__ dst, int* __restrict__ deg) {
    int e = blockIdx.x * blockDim.x + threadIdx.x;
    if (e >= E_TOT) return;
    int d = (e < N_EDGES) ? dst[e] : (e - N_EDGES);
    atomicAdd(&deg[d], 1);
}

__global__ __launch_bounds__(256) void deg_partial_kernel(const int* __restrict__ deg,
                                                          int* __restrict__ psum) {
    __shared__ int sm[256];
    int t = threadIdx.x;
    int idx = blockIdx.x * 256 + t;
    int v = (idx < N_NODES) ? deg[idx] : 0;
    sm[t] = v;
    __syncthreads();
    for (int off = 128; off >= 1; off >>= 1) {
        if (t < off) sm[t] += sm[t + off];
        __syncthreads();
    }
    if (t == 0) psum[blockIdx.x] = sm[0];
}

__global__ __launch_bounds__(256) void scan_partial_kernel(int* __restrict__ psum) {
    __shared__ int sm[256];
    int t = threadIdx.x;
    int v = (t < NBLK) ? psum[t] : 0;
    sm[t] = v;
    __syncthreads();
    for (int off = 1; off < 256; off <<= 1) {
        int add = (t >= off) ? sm[t - off] : 0;
        __syncthreads();
        sm[t] += add;
        __syncthreads();
    }
    if (t < NBLK) psum[t] = sm[t] - v;  // exclusive
}

__global__ __launch_bounds__(256) void rowptr_kernel(const int* __restrict__ deg,
                                                     const int* __restrict__ psum,
                                                     int* __restrict__ rowptr,
                                                     int* __restrict__ cursor) {
    __shared__ int sm[256];
    int t = threadIdx.x;
    int idx = blockIdx.x * 256 + t;
    int v = (idx < N_NODES) ? deg[idx] : 0;
    sm[t] = v;
    __syncthreads();
    for (int off = 1; off < 256; off <<= 1) {
        int add = (t >= off) ? sm[t - off] : 0;
        __syncthreads();
        sm[t] += add;
        __syncthreads();
    }
    if (idx < N_NODES) {
        int r = psum[blockIdx.x] + sm[t] - v;  // exclusive
        rowptr[idx] = r;
        cursor[idx] = r;
    }
    if (idx == 0) rowptr[N_NODES] = E_TOT;
}

__global__ void scatter_kernel(const int* __restrict__ srcrow, const int* __restrict__ dstrow,
                               int* __restrict__ cursor, int* __restrict__ src_sorted) {
    int e = blockIdx.x * blockDim.x + threadIdx.x;
    if (e >= E_TOT) return;
    int s, d;
    if (e < N_EDGES) { s = srcrow[e]; d = dstrow[e]; }
    else             { s = d = e - N_EDGES; }
    int pos = atomicAdd(&cursor[d], 1);
    src_sorted[pos] = s;
}

// ---------------- Layer 1 GEMM: [N,5] @ [5,512] -> bf16 h ----------------
__global__ void gemm5_kernel(const float* __restrict__ x, const float* __restrict__ W,
                             unsigned short* __restrict__ h) {
    int gid = blockIdx.x * blockDim.x + threadIdx.x;
    if (gid >= N_NODES * HC) return;
    int n = gid >> 9, c = gid & 511;
    const float* xr = x + n * 5;
    float acc = xr[0] * W[c] + xr[1] * W[512 + c] + xr[2] * W[1024 + c] +
                xr[3] * W[1536 + c] + xr[4] * W[2048 + c];
    h[gid] = f2bf(acc);
}

// ---------------- W -> W^T split (hi/lo bf16): W[512][NCOL] -> Wt[NCOL][512] ----------------
template <int NCOL>
__global__ void wsplit_kernel(const float* __restrict__ W, unsigned short* __restrict__ hi,
                              unsigned short* __restrict__ lo) {
    int idx = blockIdx.x * 256 + threadIdx.x;
    if (idx >= 512 * NCOL) return;
    int k = idx / NCOL, n = idx % NCOL;
    float v = W[idx];
    unsigned short h = f2bf(v);
    unsigned short l = f2bf(v - bf2f(h));
    hi[(size_t)n * 512 + k] = h;
    lo[(size_t)n * 512 + k] = l;
}

// ---------------- mixed-precision MFMA GEMM: bf16 A x (hi+lo) W, BK=64 ----------------
// A: [M][512] bf16 row-major (activations, already bf16-rounded upstream).
// B: [Ncols][512] bf16 hi/lo pair (W^T, fp32-class weights). C: [M][Nout] bf16.
// LDS rows of 64B; 16B-slot p holds k-chunk g = p ^ ((row>>1)&3) (zero-conflict, R5-measured).
// Full 128B-line staging per row via back-to-back half-chunks (R6).
template <int ROWS, int NW>
__device__ __forceinline__ void stage_pair(const unsigned short* __restrict__ src, int row0,
                                           int maxRow, int k0, char* lds0, char* lds1,
                                           int wave, int lane) {
    constexpr int CHUNKS = ROWS / 16;  // 1KB chunks (16 rows x 64B) per half
    for (int c = wave; c < CHUNKS; c += NW) {
        int r = c * 16 + (lane >> 2);
        int p = lane & 3;
        int g = p ^ ((r >> 1) & 3);
        int gr = row0 + r;
        if (gr > maxRow) gr = maxRow;  // tail clamp; result write-guarded
        const unsigned short* gp = src + (size_t)gr * 512 + k0 + g * 8;
        __builtin_amdgcn_global_load_lds((const __attribute__((address_space(1))) void*)gp,
                                         (__attribute__((address_space(3))) void*)(lds0 + c * 1024),
                                         16, 0, 0);
        __builtin_amdgcn_global_load_lds((const __attribute__((address_space(1))) void*)(gp + 32),
                                         (__attribute__((address_space(3))) void*)(lds1 + c * 1024),
                                         16, 0, 0);
    }
}

template <int BM, int BN, int WM, int WN>
__global__ __launch_bounds__(WM * WN * 64) void gemm_mfma(
    const unsigned short* __restrict__ A,
    const unsigned short* __restrict__ Bhi, const unsigned short* __restrict__ Blo,
    unsigned short* __restrict__ C, int M, int Nout, int maxRowB) {
    constexpr int NW = WM * WN;
    constexpr int MI = BM / (16 * WM);
    constexpr int NI = BN / (16 * WN);
    constexpr int ABYTES = BM * 64;
    constexpr int BBYTES = BN * 64;
    __shared__ __attribute__((aligned(16))) char lds[ABYTES * 2 + BBYTES * 4];
    char* const pA0   = lds;
    char* const pA1   = pA0 + ABYTES;
    char* const pBhi0 = pA1 + ABYTES;
    char* const pBhi1 = pBhi0 + BBYTES;
    char* const pBlo0 = pBhi1 + BBYTES;
    char* const pBlo1 = pBlo0 + BBYTES;

    const int t = threadIdx.x, lane = t & 63, wave = t >> 6;
    const int wr = wave / WN, wc = wave % WN;
    const int m0 = blockIdx.y * BM, n0 = blockIdx.x * BN;

    int offA[MI], offB[NI];
#pragma unroll
    for (int s = 0; s < MI; ++s) {
        int rA = (wr * MI + s) * 16 + (lane & 15);
        offA[s] = rA * 64 + ((((lane >> 4) ^ ((rA >> 1) & 3))) << 4);
    }
#pragma unroll
    for (int s = 0; s < NI; ++s) {
        int rB = (wc * NI + s) * 16 + (lane & 15);
        offB[s] = rB * 64 + ((((lane >> 4) ^ ((rB >> 1) & 3))) << 4);
    }

    f32x4 acc[MI][NI] = {};

    for (int k0 = 0; k0 < 512; k0 += 64) {
        stage_pair<BM, NW>(A,   m0, M - 1,   k0, pA0,   pA1,   wave, lane);
        stage_pair<BN, NW>(Bhi, n0, maxRowB, k0, pBhi0, pBhi1, wave, lane);
        stage_pair<BN, NW>(Blo, n0, maxRowB, k0, pBlo0, pBlo1, wave, lane);
        __syncthreads();  // compiler drains vmcnt before barrier -> LDS valid

#pragma unroll
        for (int half = 0; half < 2; ++half) {
            const char* cA   = half ? pA1   : pA0;
            const char* cBhi = half ? pBhi1 : pBhi0;
            const char* cBlo = half ? pBlo1 : pBlo0;
            bf16x8 av[MI], bh[NI], bl[NI];
#pragma unroll
            for (int s = 0; s < MI; ++s) av[s] = *(const bf16x8*)(cA + offA[s]);
#pragma unroll
            for (int s = 0; s < NI; ++s) {
                bh[s] = *(const bf16x8*)(cBhi + offB[s]);
                bl[s] = *(const bf16x8*)(cBlo + offB[s]);
            }
#pragma unroll
            for (int i = 0; i < MI; ++i)
#pragma unroll
                for (int j = 0; j < NI; ++j) {
                    acc[i][j] = __builtin_amdgcn_mfma_f32_16x16x32_bf16(av[i], bh[j], acc[i][j], 0, 0, 0);
                    acc[i][j] = __builtin_amdgcn_mfma_f32_16x16x32_bf16(av[i], bl[j], acc[i][j], 0, 0, 0);
                }
        }
        __syncthreads();
    }

    // C/D layout (m89-verified): col = lane&15, row = (lane>>4)*4 + reg
#pragma unroll
    for (int i = 0; i < MI; ++i) {
        int row = m0 + (wr * MI + i) * 16 + ((lane >> 4) << 2);
#pragma unroll
        for (int j = 0; j < NI; ++j) {
            int col = n0 + (wc * NI + j) * 16 + (lane & 15);
            f32x4 v = acc[i][j];
#pragma unroll
            for (int r = 0; r < 4; ++r) {
                if (row + r < M) C[(size_t)(row + r) * Nout + col] = f2bf(v[r]);
            }
        }
    }
}

// ---------------- attention scores from bf16 h: s_src/s_dst [N,H] ----------------
template <int H>
__global__ void score_kernel(const unsigned short* __restrict__ h,
                             const float* __restrict__ a_src, const float* __restrict__ a_dst,
                             float* __restrict__ ssrc, float* __restrict__ sdst) {
    int gid = blockIdx.x * blockDim.x + threadIdx.x;
    if (gid >= N_NODES * H) return;
    int n = gid / H, hh = gid % H;
    const unsigned short* hp = h + (size_t)n * (H * 64) + hh * 64;
    const float* asp = a_src + hh * 64;
    const float* adp = a_dst + hh * 64;
    float s1 = 0.f, s2 = 0.f;
#pragma unroll
    for (int k = 0; k < 64; k += 8) {
        uint4 hv = *(const uint4*)(hp + k);
        const unsigned u[4] = {hv.x, hv.y, hv.z, hv.w};
#pragma unroll
        for (int q = 0; q < 4; ++q) {
            float f0 = bf2f((unsigned short)(u[q] & 0xffff));
            float f1 = bf2f((unsigned short)(u[q] >> 16));
            s1 = fmaf(f0, asp[k + 2 * q], fmaf(f1, asp[k + 2 * q + 1], s1));
            s2 = fmaf(f0, adp[k + 2 * q], fmaf(f1, adp[k + 2 * q + 1], s2));
        }
    }
    ssrc[gid] = s1;
    sdst[gid] = s2;
}

// ---------------- per-(dst,head) softmax ----------------
template <int H>
__global__ void softmax_kernel(const int* __restrict__ rowptr, const int* __restrict__ srcs,
                               const float* __restrict__ ssrc, const float* __restrict__ sdst,
                               float* __restrict__ p, float* __restrict__ rden) {
    int gid = blockIdx.x * blockDim.x + threadIdx.x;
    if (gid >= N_NODES * H) return;
    int n = gid / H, hh = gid % H;
    int lo = rowptr[n], hi = rowptr[n + 1];
    float sd = sdst[gid];
    float m0 = -3.4e38f, m1 = -3.4e38f, m2 = -3.4e38f, m3 = -3.4e38f;
    int j = lo;
    for (; j + 4 <= hi; j += 4) {
        int s0 = srcs[j], s1 = srcs[j + 1], s2 = srcs[j + 2], s3 = srcs[j + 3];
        float v0 = ssrc[s0 * H + hh] + sd;
        float v1 = ssrc[s1 * H + hh] + sd;
        float v2 = ssrc[s2 * H + hh] + sd;
        float v3 = ssrc[s3 * H + hh] + sd;
        v0 = v0 > 0.f ? v0 : 0.2f * v0;
        v1 = v1 > 0.f ? v1 : 0.2f * v1;
        v2 = v2 > 0.f ? v2 : 0.2f * v2;
        v3 = v3 > 0.f ? v3 : 0.2f * v3;
        p[(size_t)j * H + hh] = v0;
        p[(size_t)(j + 1) * H + hh] = v1;
        p[(size_t)(j + 2) * H + hh] = v2;
        p[(size_t)(j + 3) * H + hh] = v3;
        m0 = fmaxf(m0, v0); m1 = fmaxf(m1, v1);
        m2 = fmaxf(m2, v2); m3 = fmaxf(m3, v3);
    }
    for (; j < hi; ++j) {
        float v = ssrc[srcs[j] * H + hh] + sd;
        v = v > 0.f ? v : 0.2f * v;
        p[(size_t)j * H + hh] = v;
        m0 = fmaxf(m0, v);
    }
    float mx = fmaxf(fmaxf(m0, m1), fmaxf(m2, m3));
    float sum = 0.f;
    for (j = lo; j < hi; ++j) {
        float pe = __expf(p[(size_t)j * H + hh] - mx);
        p[(size_t)j * H + hh] = pe;
        sum += pe;
    }
    rden[gid] = 1.f / (sum + 1e-16f);
}

// ---------------- gather-aggregate (8 heads, 512 ch, bf16 h) + bias + ELU -> bf16 out ----------
__global__ __launch_bounds__(256) void agg8_kernel(const unsigned short* __restrict__ h,
                                                   const float* __restrict__ p,
                                                   const int* __restrict__ rowptr,
                                                   const int* __restrict__ srcs,
                                                   const float* __restrict__ rden,
                                                   const float* __restrict__ bias,
                                                   unsigned short* __restrict__ out) {
    int n = blockIdx.x;
    int t = threadIdx.x;           // pair index: channels 2t, 2t+1 (same head)
    int hh = t >> 5;               // (2t)/64
    int lo = rowptr[n], hi = rowptr[n + 1];
    float rd = rden[n * 8 + hh];
    float a0 = 0.f, a1 = 0.f, b0 = 0.f, b1 = 0.f;
    float c0 = 0.f, c1 = 0.f, d0 = 0.f, d1 = 0.f;
    int j = lo;
    for (; j + 4 <= hi; j += 4) {
        int s0 = srcs[j], s1 = srcs[j + 1], s2 = srcs[j + 2], s3 = srcs[j + 3];
        unsigned v0 = *(const unsigned*)(h + (size_t)s0 * 512 + 2 * t);
        unsigned v1 = *(const unsigned*)(h + (size_t)s1 * 512 + 2 * t);
        unsigned v2 = *(const unsigned*)(h + (size_t)s2 * 512 + 2 * t);
        unsigned v3 = *(const unsigned*)(h + (size_t)s3 * 512 + 2 * t);
        float p0 = p[(size_t)j * 8 + hh];
        float p1 = p[(size_t)(j + 1) * 8 + hh];
        float p2 = p[(size_t)(j + 2) * 8 + hh];
        float p3 = p[(size_t)(j + 3) * 8 + hh];
        a0 = fmaf(p0, bf2f((unsigned short)(v0 & 0xffff)), a0);
        a1 = fmaf(p0, bf2f((unsigned short)(v0 >> 16)), a1);
        b0 = fmaf(p1, bf2f((unsigned short)(v1 & 0xffff)), b0);
        b1 = fmaf(p1, bf2f((unsigned short)(v1 >> 16)), b1);
        c0 = fmaf(p2, bf2f((unsigned short)(v2 & 0xffff)), c0);
        c1 = fmaf(p2, bf2f((unsigned short)(v2 >> 16)), c1);
        d0 = fmaf(p3, bf2f((unsigned short)(v3 & 0xffff)), d0);
        d1 = fmaf(p3, bf2f((unsigned short)(v3 >> 16)), d1);
    }
    for (; j < hi; ++j) {
        int s = srcs[j];
        unsigned v = *(const unsigned*)(h + (size_t)s * 512 + 2 * t);
        float pj = p[(size_t)j * 8 + hh];
        a0 = fmaf(pj, bf2f((unsigned short)(v & 0xffff)), a0);
        a1 = fmaf(pj, bf2f((unsigned short)(v >> 16)), a1);
    }
    float s0 = (a0 + b0) + (c0 + d0);
    float s1 = (a1 + b1) + (c1 + d1);
    float2 bv = *(const float2*)(bias + 2 * t);
    float v0 = elu1(s0 * rd + bv.x);
    float v1 = elu1(s1 * rd + bv.y);
    unsigned pack = (unsigned)f2bf(v0) | ((unsigned)f2bf(v1) << 16);
    *(unsigned*)(out + (size_t)n * 512 + 2 * t) = pack;
}

// ---------------- gather-aggregate (1 head, 64 ch, bf16 h) + bias + ELU -> fp32 ----------------
__global__ __launch_bounds__(64) void agg1_kernel(const unsigned short* __restrict__ h,
                                                  const float* __restrict__ p,
                                                  const int* __restrict__ rowptr,
                                                  const int* __restrict__ srcs,
                                                  const float* __restrict__ rden,
                                                  const float* __restrict__ bias,
                                                  float* __restrict__ out) {
    int n = blockIdx.x;
    int t = threadIdx.x;
    int lo = rowptr[n], hi = rowptr[n + 1];
    float rd = rden[n];
    float a = 0.f, b = 0.f, c = 0.f, d = 0.f;
    int j = lo;
    for (; j + 4 <= hi; j += 4) {
        int s0 = srcs[j], s1 = srcs[j + 1], s2 = srcs[j + 2], s3 = srcs[j + 3];
        float h0 = bf2f(h[(size_t)s0 * 64 + t]);
        float h1 = bf2f(h[(size_t)s1 * 64 + t]);
        float h2 = bf2f(h[(size_t)s2 * 64 + t]);
        float h3 = bf2f(h[(size_t)s3 * 64 + t]);
        a = fmaf(p[j], h0, a);
        b = fmaf(p[j + 1], h1, b);
        c = fmaf(p[j + 2], h2, c);
        d = fmaf(p[j + 3], h3, d);
    }
    for (; j < hi; ++j) {
        a = fmaf(p[j], bf2f(h[(size_t)srcs[j] * 64 + t]), a);
    }
    float acc = (a + b) + (c + d);
    out[(size_t)n * 64 + t] = elu1(acc * rd + bias[t]);
}

// ---------------- classifier: sigmoid(h3 @ Wc + bc) ----------------
__global__ void cls_kernel(const float* __restrict__ h, const float* __restrict__ Wc,
                           const float* __restrict__ bc, float* __restrict__ out) {
    int n = blockIdx.x * blockDim.x + threadIdx.x;
    if (n >= N_NODES) return;
    const float* hp = h + (size_t)n * 64;
    float s = bc[0];
#pragma unroll
    for (int k = 0; k < 64; k += 4) {
        float4 hv = *(const float4*)(hp + k);
        float4 wv = *(const float4*)(Wc + k);
        s += hv.x * wv.x + hv.y * wv.y + hv.z * wv.z + hv.w * wv.w;
    }
    out[n] = 1.f / (1.f + __expf(-s));
}

extern "C" void kernel_launch(void* const* d_in, const int* in_sizes, int n_in,
                              void* d_out, int out_size, void* d_ws, size_t ws_size,
                              hipStream_t stream) {
    const float* x   = (const float*)d_in[0];
    const int*   ei  = (const int*)d_in[1];
    const int* src_row = ei;
    const int* dst_row = ei + N_EDGES;
    const float* W1  = (const float*)d_in[2];
    const float* as1 = (const float*)d_in[3];
    const float* ad1 = (const float*)d_in[4];
    const float* b1  = (const float*)d_in[5];
    const float* W2  = (const float*)d_in[6];
    const float* as2 = (const float*)d_in[7];
    const float* ad2 = (const float*)d_in[8];
    const float* b2  = (const float*)d_in[9];
    const float* W3  = (const float*)d_in[10];
    const float* as3 = (const float*)d_in[11];
    const float* ad3 = (const float*)d_in[12];
    const float* b3  = (const float*)d_in[13];
    const float* Wc  = (const float*)d_in[14];
    const float* bc  = (const float*)d_in[15];

    char* w = (char*)d_ws;
    auto alloc = [&](size_t bytes) -> void* {
        void* ptr = (void*)w;
        w += (bytes + 255) & ~(size_t)255;
        return ptr;
    };
    int*   deg    = (int*)alloc((size_t)N_NODES * 4);
    int*   rowptr = (int*)alloc((size_t)(N_NODES + 1) * 4);
    int*   cursor = (int*)alloc((size_t)N_NODES * 4);
    int*   srcs   = (int*)alloc((size_t)E_TOT * 4);
    int*   psum   = (int*)alloc((size_t)NBLK * 4);
    float* pbuf   = (float*)alloc((size_t)E_TOT * HEADS * 4);
    float* ssrc   = (float*)alloc((size_t)N_NODES * HEADS * 4);
    float* sdst   = (float*)alloc((size_t)N_NODES * HEADS * 4);
    float* rden   = (float*)alloc((size_t)N_NODES * HEADS * 4);
    unsigned short* hbf = (unsigned short*)alloc((size_t)N_NODES * HC * 2);  // bf16 h (GEMM out)
    unsigned short* gbf = (unsigned short*)alloc((size_t)N_NODES * HC * 2);  // agg out (bf16)
    float* g3 = (float*)alloc((size_t)N_NODES * 64 * 4);                     // layer-3 agg out
    unsigned short* w2thi = (unsigned short*)alloc((size_t)512 * 512 * 2);
    unsigned short* w2tlo = (unsigned short*)alloc((size_t)512 * 512 * 2);
    unsigned short* w3thi = (unsigned short*)alloc((size_t)64 * 512 * 2);
    unsigned short* w3tlo = (unsigned short*)alloc((size_t)64 * 512 * 2);

    hipMemsetAsync(deg, 0, (size_t)N_NODES * 4, stream);

    const int EB = (E_TOT + 255) / 256;
    hist_kernel<<<EB, 256, 0, stream>>>(dst_row, deg);
    deg_partial_kernel<<<NBLK, 256, 0, stream>>>(deg, psum);
    scan_partial_kernel<<<1, 256, 0, stream>>>(psum);
    rowptr_kernel<<<NBLK, 256, 0, stream>>>(deg, psum, rowptr, cursor);
    scatter_kernel<<<EB, 256, 0, stream>>>(src_row, dst_row, cursor, srcs);

    // weight transpose+split (tiny; once per call)
    wsplit_kernel<512><<<(512 * 512 + 255) / 256, 256, 0, stream>>>(W2, w2thi, w2tlo);
    wsplit_kernel<64><<<(512 * 64 + 255) / 256, 256, 0, stream>>>(W3, w3thi, w3tlo);

    const int NHB = (N_NODES * HEADS + 255) / 256;
    const int NB  = (N_NODES + 255) / 256;
    const int MB128 = (N_NODES + 127) / 128;  // 391
    const int MB64  = (N_NODES + 63) / 64;    // 782

    // ---- layer 1: x[N,5] -> hbf[N,512] -> attn -> gbf ----
    gemm5_kernel<<<(N_NODES * HC + 255) / 256, 256, 0, stream>>>(x, W1, hbf);
    score_kernel<8><<<NHB, 256, 0, stream>>>(hbf, as1, ad1, ssrc, sdst);
    softmax_kernel<8><<<NHB, 256, 0, stream>>>(rowptr, srcs, ssrc, sdst, pbuf, rden);
    agg8_kernel<<<N_NODES, 256, 0, stream>>>(hbf, pbuf, rowptr, srcs, rden, b1, gbf);

    // ---- layer 2: gbf @ W2 (bf16 x hi/lo MFMA, BK=64) -> hbf -> attn -> gbf ----
    gemm_mfma<128, 128, 2, 2><<<dim3(4, MB128), 256, 0, stream>>>(gbf, w2thi, w2tlo, hbf,
                                                                  N_NODES, 512, 511);
    score_kernel<8><<<NHB, 256, 0, stream>>>(hbf, as2, ad2, ssrc, sdst);
    softmax_kernel<8><<<NHB, 256, 0, stream>>>(rowptr, srcs, ssrc, sdst, pbuf, rden);
    agg8_kernel<<<N_NODES, 256, 0, stream>>>(hbf, pbuf, rowptr, srcs, rden, b2, gbf);

    // ---- layer 3: gbf @ W3 (BM=64 for parallelism) -> hbf[N,64] -> attn -> g3 ----
    gemm_mfma<64, 64, 2, 1><<<dim3(1, MB64), 128, 0, stream>>>(gbf, w3thi, w3tlo, hbf,
                                                               N_NODES, 64, 63);
    score_kernel<1><<<NB, 256, 0, stream>>>(hbf, as3, ad3, ssrc, sdst);
    softmax_kernel<1><<<NB, 256, 0, stream>>>(rowptr, srcs, ssrc, sdst, pbuf, rden);
    agg1_kernel<<<N_NODES, 64, 0, stream>>>(hbf, pbuf, rowptr, srcs, rden, b3, g3);

    // ---- classifier ----
    cls_kernel<<<NB, 256, 0, stream>>>(g3, Wc, bc, (float*)d_out);
}